// Round 2
// baseline (681.743 us; speedup 1.0000x reference)
//
#include <hip/hip_runtime.h>
#include <hip/hip_bf16.h>

#define S_LEN 2048
#define BATCH 2
#define EDIM 1024
#define NHEAD 16
#define DHEAD 64
#define HIDDEN 512
#define SIGD 64
#define KEEP 12           // NUM_HEADS - INACTIVE

typedef __attribute__((ext_vector_type(8))) short bf16x8;
typedef __attribute__((ext_vector_type(4))) float f32x4;

static __device__ __forceinline__ float bf2f(short s) {
  unsigned int u = ((unsigned int)(unsigned short)s) << 16;
  float f; __builtin_memcpy(&f, &u, 4); return f;
}
static __device__ __forceinline__ short f2bf(float f) {
  unsigned int u; __builtin_memcpy(&u, &f, 4);
  u += 0x7fffu + ((u >> 16) & 1u);   // round-to-nearest-even
  return (short)(u >> 16);
}
static __device__ __forceinline__ void split2(float x, short& h, short& l) {
  h = f2bf(x);
  l = f2bf(x - bf2f(h));
}

// query fp32 -> bf16 (4 elems/thread)
__global__ __launch_bounds__(256) void cvt_bf16_kernel(
    const float* __restrict__ in, short* __restrict__ out)
{
  int i = (blockIdx.x * 256 + threadIdx.x) * 4;
  float4 f = *(const float4*)(in + i);
  union { short s[4]; uint2 v; } u;
  u.s[0] = f2bf(f.x); u.s[1] = f2bf(f.y); u.s[2] = f2bf(f.z); u.s[3] = f2bf(f.w);
  *(uint2*)(out + i) = u.v;
}

// C = A @ W^T + bias.  A: M x 1024 bf16 row-major. W: N x 1024 FP32 row-major
// (converted to bf16 inline during staging). bias fp32.
// MODE 0: (acc+b)*0.125 -> bf16. MODE 1: acc+b -> bf16. MODE 3: acc+b -> fp32.
template<int MODE>
__global__ __launch_bounds__(256) void gemm_aw(
    const short* __restrict__ A, const float* __restrict__ W,
    const float* __restrict__ bias, void* __restrict__ outv)
{
  const int K = EDIM;
  __shared__ short As[64][32];
  __shared__ short Bs[64][32];
  const int tid  = threadIdx.x;
  const int wave = tid >> 6;
  const int lane = tid & 63;
  const int quad = lane >> 4, l16 = lane & 15;
  const int row0 = blockIdx.x * 64, col0 = blockIdx.y * 64;
  const int lr = tid >> 2, lc = (tid & 3) * 8;
  f32x4 acc0 = {}, acc1 = {}, acc2 = {}, acc3 = {};
  const size_t aoff = (size_t)(row0 + lr) * K + lc;
  const size_t woff = (size_t)(col0 + lr) * K + lc;
  for (int k0 = 0; k0 < K; k0 += 32) {
    __syncthreads();
    *(uint4*)(&As[lr][lc]) = *(const uint4*)(A + aoff + k0);
    {
      const float* src = W + woff + k0;
      float4 f0 = *(const float4*)src;
      float4 f1 = *(const float4*)(src + 4);
      union { short s[8]; uint4 v; } u;
      u.s[0] = f2bf(f0.x); u.s[1] = f2bf(f0.y); u.s[2] = f2bf(f0.z); u.s[3] = f2bf(f0.w);
      u.s[4] = f2bf(f1.x); u.s[5] = f2bf(f1.y); u.s[6] = f2bf(f1.z); u.s[7] = f2bf(f1.w);
      *(uint4*)(&Bs[lr][lc]) = u.v;
    }
    __syncthreads();
    bf16x8 a  = *(const bf16x8*)(&As[wave*16 + l16][quad*8]);
    bf16x8 b0 = *(const bf16x8*)(&Bs[0*16 + l16][quad*8]);
    bf16x8 b1 = *(const bf16x8*)(&Bs[1*16 + l16][quad*8]);
    bf16x8 b2 = *(const bf16x8*)(&Bs[2*16 + l16][quad*8]);
    bf16x8 b3 = *(const bf16x8*)(&Bs[3*16 + l16][quad*8]);
    acc0 = __builtin_amdgcn_mfma_f32_16x16x32_bf16(a, b0, acc0, 0, 0, 0);
    acc1 = __builtin_amdgcn_mfma_f32_16x16x32_bf16(a, b1, acc1, 0, 0, 0);
    acc2 = __builtin_amdgcn_mfma_f32_16x16x32_bf16(a, b2, acc2, 0, 0, 0);
    acc3 = __builtin_amdgcn_mfma_f32_16x16x32_bf16(a, b3, acc3, 0, 0, 0);
  }
  f32x4 accs[4] = {acc0, acc1, acc2, acc3};
  #pragma unroll
  for (int c = 0; c < 4; ++c) {
    int col = col0 + c*16 + l16;
    float bv = bias[col];
    #pragma unroll
    for (int r = 0; r < 4; ++r) {
      int row = row0 + wave*16 + quad*4 + r;
      float v = accs[c][r] + bv;
      if (MODE == 0) v *= 0.125f;                 // D^-0.5 = 64^-0.5
      if constexpr (MODE == 3) {
        ((float*)outv)[(size_t)row * EDIM + col] = v;
      } else {
        ((short*)outv)[(size_t)row * EDIM + col] = f2bf(v);
      }
    }
  }
}

// Fused: t1 = relu(query @ inf1_w^T + b) via hi/lo-split bf16 MFMA (fp32-accurate),
// t2 = t1 @ inf2_w^T + b, s = t2 @ head_sig^T, mask = top-12 indicator.
// 16 tokens per block, 256 blocks.
__global__ __launch_bounds__(256) void mask_fused(
    const float* __restrict__ query,    // 4096 x 1024 fp32
    const float* __restrict__ inf1_w,   // 512 x 1024 fp32
    const float* __restrict__ inf1_b,   // 512 fp32
    const float* __restrict__ inf2_w,   // 64 x 512 fp32
    const float* __restrict__ inf2_b,   // 64 fp32
    const float* __restrict__ head_sig, // 16 x 64 fp32
    float* __restrict__ maskbuf)        // (B*NHEAD) x S_LEN fp32
{
  __shared__ float t1s[16][HIDDEN];       // 32 KB
  __shared__ short Ah[16][32], Al[16][32];
  __shared__ short Bh[64][32], Bl[64][32];
  __shared__ float t2s[16][SIGD];
  __shared__ float ss[16][NHEAD];
  const int tid = threadIdx.x;
  const int wave = tid >> 6, lane = tid & 63;
  const int quad = lane >> 4, l16 = lane & 15;
  const int r0 = blockIdx.x * 16;          // token rows

  for (int hb = 0; hb < 8; ++hb) {         // 64-wide column block of t1
    f32x4 acc = {};
    for (int k0 = 0; k0 < EDIM; k0 += 32) {
      __syncthreads();
      if (tid < 64) {                       // stage A 16x32 hi/lo
        int r = tid >> 2, c8 = (tid & 3) * 8;
        const float* src = query + (size_t)(r0 + r) * EDIM + k0 + c8;
        union { short s[8]; uint4 v; } uh, ul;
        #pragma unroll
        for (int u = 0; u < 8; ++u) split2(src[u], uh.s[u], ul.s[u]);
        *(uint4*)(&Ah[r][c8]) = uh.v;
        *(uint4*)(&Al[r][c8]) = ul.v;
      }
      {                                     // stage B 64x32 hi/lo
        int r = tid >> 2, c8 = (tid & 3) * 8;
        const float* src = inf1_w + (size_t)(hb*64 + r) * EDIM + k0 + c8;
        union { short s[8]; uint4 v; } uh, ul;
        #pragma unroll
        for (int u = 0; u < 8; ++u) split2(src[u], uh.s[u], ul.s[u]);
        *(uint4*)(&Bh[r][c8]) = uh.v;
        *(uint4*)(&Bl[r][c8]) = ul.v;
      }
      __syncthreads();
      bf16x8 ah = *(const bf16x8*)(&Ah[l16][quad*8]);
      bf16x8 al = *(const bf16x8*)(&Al[l16][quad*8]);
      bf16x8 bh = *(const bf16x8*)(&Bh[wave*16 + l16][quad*8]);
      bf16x8 bl = *(const bf16x8*)(&Bl[wave*16 + l16][quad*8]);
      acc = __builtin_amdgcn_mfma_f32_16x16x32_bf16(ah, bh, acc, 0, 0, 0);
      acc = __builtin_amdgcn_mfma_f32_16x16x32_bf16(ah, bl, acc, 0, 0, 0);
      acc = __builtin_amdgcn_mfma_f32_16x16x32_bf16(al, bh, acc, 0, 0, 0);
    }
    int col = hb*64 + wave*16 + l16;
    float bv = inf1_b[col];
    #pragma unroll
    for (int r = 0; r < 4; ++r)
      t1s[quad*4 + r][col] = fmaxf(acc[r] + bv, 0.0f);
  }
  __syncthreads();
  // t2: 16 tok x 64 sig, 4 items per thread, fp32
  #pragma unroll
  for (int it = 0; it < 4; ++it) {
    int idx = tid + it * 256;
    int tok = idx >> 6, j = idx & 63;
    const float4* w4 = (const float4*)(inf2_w + (size_t)j * HIDDEN);
    const float4* t4 = (const float4*)(&t1s[tok][0]);
    float a = inf2_b[j];
    for (int k = 0; k < HIDDEN/4; ++k) {
      float4 wv = w4[k], tv = t4[k];
      a += tv.x*wv.x + tv.y*wv.y + tv.z*wv.z + tv.w*wv.w;
    }
    t2s[tok][j] = a;
  }
  __syncthreads();
  {
    int tok = tid >> 4, h = tid & 15;
    float a = 0.f;
    for (int d = 0; d < SIGD; ++d) a += t2s[tok][d] * head_sig[h*SIGD + d];
    ss[tok][h] = a;
  }
  __syncthreads();
  {
    int tok = tid >> 4, h = tid & 15;
    float sv = ss[tok][h];
    int cnt = 0;
    #pragma unroll
    for (int j = 0; j < NHEAD; ++j) cnt += (ss[tok][j] > sv) ? 1 : 0;
    int gt = r0 + tok;
    int s = gt >> 1, b = gt & 1;             // token row = s*B + b
    maskbuf[((size_t)(b*NHEAD + h)) * S_LEN + s] = (cnt < KEEP) ? 1.0f : 0.0f;
  }
}

// Flash attention, one block per (b,h, 64-row q-tile). Q pre-scaled.
// Writes gated O (bf16) IN-PLACE over the Q buffer (each block is the sole
// reader of the region it writes, and reads it into LDS before writing).
__global__ __launch_bounds__(256) void flash_attn(
    short* QpOg,                               // read Q, write gated O
    const short* __restrict__ Kp, const short* __restrict__ Vp,
    const float* __restrict__ maskbuf)
{
  __shared__ short Qs[64][64];
  __shared__ short Ks[64][64];
  __shared__ short Vt[64][64];      // transposed: Vt[d][n]
  __shared__ short Ps[4][16][64];   // per-wave P tile
  const int bh = blockIdx.x;
  const int b = bh >> 4, h = bh & 15;
  const int q0 = blockIdx.y * 64;
  const int tid = threadIdx.x;
  const int wave = tid >> 6, lane = tid & 63;
  const int quad = lane >> 4, l16 = lane & 15;
  const size_t colbase = (size_t)b * EDIM + h * DHEAD;
  const size_t rstride = (size_t)BATCH * EDIM;   // 2048
  {
    int r = tid >> 2, d0 = (tid & 3) * 16;
    const short* src = QpOg + (size_t)(q0 + r) * rstride + colbase + d0;
    *(uint4*)&Qs[r][d0]     = *(const uint4*)src;
    *(uint4*)&Qs[r][d0 + 8] = *(const uint4*)(src + 8);
  }
  float m_i[4], l_i[4];
  f32x4 oacc[4];
  #pragma unroll
  for (int r = 0; r < 4; ++r) { m_i[r] = -1e30f; l_i[r] = 0.f; }
  #pragma unroll
  for (int dt = 0; dt < 4; ++dt) oacc[dt] = f32x4{0.f, 0.f, 0.f, 0.f};

  for (int kv0 = 0; kv0 < S_LEN; kv0 += 64) {
    __syncthreads();
    {
      int r = tid >> 2, d0 = (tid & 3) * 16;
      const short* src = Kp + (size_t)(kv0 + r) * rstride + colbase + d0;
      *(uint4*)&Ks[r][d0]     = *(const uint4*)src;
      *(uint4*)&Ks[r][d0 + 8] = *(const uint4*)(src + 8);
    }
    #pragma unroll
    for (int it = 0; it < 2; ++it) {
      int idx = tid + it * 256;
      int n = idx >> 3, d0 = (idx & 7) * 8;
      uint4 vv = *(const uint4*)(Vp + (size_t)(kv0 + n) * rstride + colbase + d0);
      const short* vp = (const short*)&vv;
      #pragma unroll
      for (int u = 0; u < 8; ++u) Vt[d0 + u][n] = vp[u];
    }
    __syncthreads();
    f32x4 sacc[4] = {};
    #pragma unroll
    for (int ks = 0; ks < 2; ++ks) {
      bf16x8 a = *(const bf16x8*)&Qs[wave*16 + l16][ks*32 + quad*8];
      #pragma unroll
      for (int c = 0; c < 4; ++c) {
        bf16x8 bb = *(const bf16x8*)&Ks[c*16 + l16][ks*32 + quad*8];
        sacc[c] = __builtin_amdgcn_mfma_f32_16x16x32_bf16(a, bb, sacc[c], 0, 0, 0);
      }
    }
    float p[4][4];
    #pragma unroll
    for (int r = 0; r < 4; ++r) {
      float vmax = fmaxf(fmaxf(sacc[0][r], sacc[1][r]), fmaxf(sacc[2][r], sacc[3][r]));
      #pragma unroll
      for (int off = 1; off < 16; off <<= 1) vmax = fmaxf(vmax, __shfl_xor(vmax, off, 64));
      float mnew = fmaxf(m_i[r], vmax);
      float alpha = __expf(m_i[r] - mnew);
      float rsum = 0.f;
      #pragma unroll
      for (int c = 0; c < 4; ++c) {
        float pv = bf2f(f2bf(__expf(sacc[c][r] - mnew)));  // keep l consistent with bf16 P
        p[c][r] = pv; rsum += pv;
      }
      #pragma unroll
      for (int off = 1; off < 16; off <<= 1) rsum += __shfl_xor(rsum, off, 64);
      l_i[r] = l_i[r] * alpha + rsum;
      m_i[r] = mnew;
      #pragma unroll
      for (int dt = 0; dt < 4; ++dt) oacc[dt][r] *= alpha;
    }
    #pragma unroll
    for (int c = 0; c < 4; ++c)
      #pragma unroll
      for (int r = 0; r < 4; ++r)
        Ps[wave][quad*4 + r][c*16 + l16] = f2bf(p[c][r]);
    __syncthreads();
    #pragma unroll
    for (int ks = 0; ks < 2; ++ks) {
      bf16x8 a = *(const bf16x8*)&Ps[wave][l16][ks*32 + quad*8];
      #pragma unroll
      for (int dt = 0; dt < 4; ++dt) {
        bf16x8 bb = *(const bf16x8*)&Vt[dt*16 + l16][ks*32 + quad*8];
        oacc[dt] = __builtin_amdgcn_mfma_f32_16x16x32_bf16(a, bb, oacc[dt], 0, 0, 0);
      }
    }
  }
  #pragma unroll
  for (int r = 0; r < 4; ++r) {
    int s = q0 + wave*16 + quad*4 + r;
    float mk = maskbuf[((size_t)(b*NHEAD + h)) * S_LEN + s];
    float scale = mk / l_i[r];
    short* dst = QpOg + (size_t)s * rstride + colbase;
    #pragma unroll
    for (int dt = 0; dt < 4; ++dt)
      dst[dt*16 + l16] = f2bf(oacc[dt][r] * scale);
  }
}

extern "C" void kernel_launch(void* const* d_in, const int* in_sizes, int n_in,
                              void* d_out, int out_size, void* d_ws, size_t ws_size,
                              hipStream_t stream)
{
  const float* query   = (const float*)d_in[0];
  const float* q_w     = (const float*)d_in[1];
  const float* q_b     = (const float*)d_in[2];
  const float* k_w     = (const float*)d_in[3];
  const float* k_b     = (const float*)d_in[4];
  const float* v_w     = (const float*)d_in[5];
  const float* v_b     = (const float*)d_in[6];
  const float* out_w   = (const float*)d_in[7];
  const float* out_b   = (const float*)d_in[8];
  const float* inf1_w  = (const float*)d_in[9];
  const float* inf1_b  = (const float*)d_in[10];
  const float* inf2_w  = (const float*)d_in[11];
  const float* inf2_b  = (const float*)d_in[12];
  const float* head_sig= (const float*)d_in[13];

  char* ws = (char*)d_ws;
  short* qh      = (short*)(ws);                       // 8 MB (dead after QKV gemms)
  float* maskbuf = (float*)(ws);                       // 256 KB, reuses qh region
  short* Qp      = (short*)(ws + (size_t)( 8u<<20));   // 8 MB (becomes gated O)
  short* Kp      = (short*)(ws + (size_t)(16u<<20));   // 8 MB
  short* Vp      = (short*)(ws + (size_t)(24u<<20));   // 8 MB  -> total exactly 32 MB
  float* out     = (float*)d_out;

  dim3 blk(256);
  cvt_bf16_kernel<<<dim3(4096), blk, 0, stream>>>(query, qh);
  gemm_aw<0><<<dim3(64,16), blk, 0, stream>>>(qh, q_w, q_b, (void*)Qp);
  gemm_aw<1><<<dim3(64,16), blk, 0, stream>>>(qh, k_w, k_b, (void*)Kp);
  gemm_aw<1><<<dim3(64,16), blk, 0, stream>>>(qh, v_w, v_b, (void*)Vp);
  // qh dead from here; its region now hosts maskbuf
  mask_fused<<<dim3(256), blk, 0, stream>>>(query, inf1_w, inf1_b, inf2_w, inf2_b,
                                            head_sig, maskbuf);
  flash_attn<<<dim3(32, 32), blk, 0, stream>>>(Qp, Kp, Vp, maskbuf);
  gemm_aw<3><<<dim3(64,16), blk, 0, stream>>>(Qp, out_w, out_b, (void*)out);
}

// Round 3
// 476.100 us; speedup vs baseline: 1.4319x; 1.4319x over previous
//
#include <hip/hip_runtime.h>
#include <hip/hip_bf16.h>

#define S_LEN 2048
#define BATCH 2
#define EDIM 1024
#define NHEAD 16
#define DHEAD 64
#define HIDDEN 512
#define SIGD 64
#define KEEP 12           // NUM_HEADS - INACTIVE

typedef __attribute__((ext_vector_type(8))) short bf16x8;
typedef __attribute__((ext_vector_type(4))) float f32x4;

static __device__ __forceinline__ float bf2f(short s) {
  unsigned int u = ((unsigned int)(unsigned short)s) << 16;
  float f; __builtin_memcpy(&f, &u, 4); return f;
}
static __device__ __forceinline__ short f2bf(float f) {
  unsigned int u; __builtin_memcpy(&u, &f, 4);
  u += 0x7fffu + ((u >> 16) & 1u);   // round-to-nearest-even
  return (short)(u >> 16);
}

// fp32 -> (hi bf16, lo bf16) split; 4 elems/thread.
__global__ __launch_bounds__(256) void cvt_split_kernel(
    const float* __restrict__ in, short* __restrict__ outh, short* __restrict__ outl)
{
  int i = (blockIdx.x * 256 + threadIdx.x) * 4;
  float4 f = *(const float4*)(in + i);
  union { short s[4]; uint2 v; } uh, ul;
  float x[4] = {f.x, f.y, f.z, f.w};
  #pragma unroll
  for (int u = 0; u < 4; ++u) {
    short h = f2bf(x[u]);
    uh.s[u] = h;
    ul.s[u] = f2bf(x[u] - bf2f(h));
  }
  *(uint2*)(outh + i) = uh.v;
  *(uint2*)(outl + i) = ul.v;
}

// C = A @ W^T + bias.  A: M x 1024 bf16 row-major. W: N x 1024 FP32 row-major
// (converted to bf16 inline during staging). bias fp32.
// MODE 0: (acc+b)*0.125 -> bf16. MODE 1: acc+b -> bf16. MODE 3: acc+b -> fp32.
template<int MODE>
__global__ __launch_bounds__(256) void gemm_aw(
    const short* __restrict__ A, const float* __restrict__ W,
    const float* __restrict__ bias, void* __restrict__ outv)
{
  const int K = EDIM;
  __shared__ short As[64][32];
  __shared__ short Bs[64][32];
  const int tid  = threadIdx.x;
  const int wave = tid >> 6;
  const int lane = tid & 63;
  const int quad = lane >> 4, l16 = lane & 15;
  const int row0 = blockIdx.x * 64, col0 = blockIdx.y * 64;
  const int lr = tid >> 2, lc = (tid & 3) * 8;
  f32x4 acc0 = {}, acc1 = {}, acc2 = {}, acc3 = {};
  const size_t aoff = (size_t)(row0 + lr) * K + lc;
  const size_t woff = (size_t)(col0 + lr) * K + lc;
  for (int k0 = 0; k0 < K; k0 += 32) {
    __syncthreads();
    *(uint4*)(&As[lr][lc]) = *(const uint4*)(A + aoff + k0);
    {
      const float* src = W + woff + k0;
      float4 f0 = *(const float4*)src;
      float4 f1 = *(const float4*)(src + 4);
      union { short s[8]; uint4 v; } u;
      u.s[0] = f2bf(f0.x); u.s[1] = f2bf(f0.y); u.s[2] = f2bf(f0.z); u.s[3] = f2bf(f0.w);
      u.s[4] = f2bf(f1.x); u.s[5] = f2bf(f1.y); u.s[6] = f2bf(f1.z); u.s[7] = f2bf(f1.w);
      *(uint4*)(&Bs[lr][lc]) = u.v;
    }
    __syncthreads();
    bf16x8 a  = *(const bf16x8*)(&As[wave*16 + l16][quad*8]);
    bf16x8 b0 = *(const bf16x8*)(&Bs[0*16 + l16][quad*8]);
    bf16x8 b1 = *(const bf16x8*)(&Bs[1*16 + l16][quad*8]);
    bf16x8 b2 = *(const bf16x8*)(&Bs[2*16 + l16][quad*8]);
    bf16x8 b3 = *(const bf16x8*)(&Bs[3*16 + l16][quad*8]);
    acc0 = __builtin_amdgcn_mfma_f32_16x16x32_bf16(a, b0, acc0, 0, 0, 0);
    acc1 = __builtin_amdgcn_mfma_f32_16x16x32_bf16(a, b1, acc1, 0, 0, 0);
    acc2 = __builtin_amdgcn_mfma_f32_16x16x32_bf16(a, b2, acc2, 0, 0, 0);
    acc3 = __builtin_amdgcn_mfma_f32_16x16x32_bf16(a, b3, acc3, 0, 0, 0);
  }
  f32x4 accs[4] = {acc0, acc1, acc2, acc3};
  #pragma unroll
  for (int c = 0; c < 4; ++c) {
    int col = col0 + c*16 + l16;
    float bv = bias[col];
    #pragma unroll
    for (int r = 0; r < 4; ++r) {
      int row = row0 + wave*16 + quad*4 + r;
      float v = accs[c][r] + bv;
      if (MODE == 0) v *= 0.125f;                 // D^-0.5 = 64^-0.5
      if constexpr (MODE == 3) {
        ((float*)outv)[(size_t)row * EDIM + col] = v;
      } else {
        ((short*)outv)[(size_t)row * EDIM + col] = f2bf(v);
      }
    }
  }
}

// t1 = relu(query @ inf1_w^T + b) with hi/lo-split inputs (3 MFMAs ~ fp32-exact).
// A,B pre-split into hi/lo bf16 global buffers. Out fp32 4096 x 512.
__global__ __launch_bounds__(256) void gemm_t1(
    const short* __restrict__ Agh, const short* __restrict__ Agl,
    const short* __restrict__ Bgh, const short* __restrict__ Bgl,
    const float* __restrict__ bias, float* __restrict__ T1)
{
  const int K = EDIM;
  __shared__ short Ah[64][32], Al[64][32];
  __shared__ short Bh[64][32], Bl[64][32];
  const int tid  = threadIdx.x;
  const int wave = tid >> 6;
  const int lane = tid & 63;
  const int quad = lane >> 4, l16 = lane & 15;
  const int row0 = blockIdx.x * 64, col0 = blockIdx.y * 64;
  const int lr = tid >> 2, lc = (tid & 3) * 8;
  f32x4 acc0 = {}, acc1 = {}, acc2 = {}, acc3 = {};
  const size_t aoff = (size_t)(row0 + lr) * K + lc;
  const size_t woff = (size_t)(col0 + lr) * K + lc;
  for (int k0 = 0; k0 < K; k0 += 32) {
    __syncthreads();
    *(uint4*)(&Ah[lr][lc]) = *(const uint4*)(Agh + aoff + k0);
    *(uint4*)(&Al[lr][lc]) = *(const uint4*)(Agl + aoff + k0);
    *(uint4*)(&Bh[lr][lc]) = *(const uint4*)(Bgh + woff + k0);
    *(uint4*)(&Bl[lr][lc]) = *(const uint4*)(Bgl + woff + k0);
    __syncthreads();
    bf16x8 ah = *(const bf16x8*)(&Ah[wave*16 + l16][quad*8]);
    bf16x8 al = *(const bf16x8*)(&Al[wave*16 + l16][quad*8]);
    #pragma unroll
    for (int c = 0; c < 4; ++c) {
      bf16x8 bh = *(const bf16x8*)(&Bh[c*16 + l16][quad*8]);
      bf16x8 bl = *(const bf16x8*)(&Bl[c*16 + l16][quad*8]);
      f32x4& acc = (c == 0) ? acc0 : (c == 1) ? acc1 : (c == 2) ? acc2 : acc3;
      acc = __builtin_amdgcn_mfma_f32_16x16x32_bf16(ah, bh, acc, 0, 0, 0);
      acc = __builtin_amdgcn_mfma_f32_16x16x32_bf16(ah, bl, acc, 0, 0, 0);
      acc = __builtin_amdgcn_mfma_f32_16x16x32_bf16(al, bh, acc, 0, 0, 0);
    }
  }
  f32x4 accs[4] = {acc0, acc1, acc2, acc3};
  #pragma unroll
  for (int c = 0; c < 4; ++c) {
    int col = col0 + c*16 + l16;
    float bv = bias[col];
    #pragma unroll
    for (int r = 0; r < 4; ++r) {
      int row = row0 + wave*16 + quad*4 + r;
      T1[(size_t)row * HIDDEN + col] = fmaxf(accs[c][r] + bv, 0.0f);
    }
  }
}

// t2 = t1 @ inf2_w^T + b ; s = t2 @ head_sig^T ; mask = top-12 indicator.
// 4 tokens per block, fp32 end-to-end (mask flips are catastrophic).
__global__ __launch_bounds__(256) void head_mask_kernel(
    const float* __restrict__ T1,        // 4096 x HIDDEN fp32
    const float* __restrict__ inf2_w,    // SIGD x HIDDEN fp32
    const float* __restrict__ inf2_b,    // SIGD fp32
    const float* __restrict__ head_sig,  // NHEAD x SIGD fp32
    float* __restrict__ maskbuf)         // (B*NHEAD) x S_LEN fp32
{
  __shared__ float t1s[4][HIDDEN];
  __shared__ float t2s[4][SIGD];
  __shared__ float ss[4][NHEAD];
  const int tid = threadIdx.x;
  const int tok0 = blockIdx.x * 4;
  {
    int rtok = tid >> 6;
    int off  = (tid & 63) * 8;
    const float* src = T1 + (size_t)(tok0 + rtok) * HIDDEN + off;
    *(float4*)&t1s[rtok][off]     = *(const float4*)(src);
    *(float4*)&t1s[rtok][off + 4] = *(const float4*)(src + 4);
  }
  __syncthreads();
  {
    int tok = tid >> 6, j = tid & 63;
    const float4* w4 = (const float4*)(inf2_w + (size_t)j * HIDDEN);
    const float4* t4 = (const float4*)(&t1s[tok][0]);
    float a = inf2_b[j];
    for (int k = 0; k < HIDDEN/4; ++k) {
      float4 wv = w4[k], tv = t4[k];
      a += tv.x*wv.x + tv.y*wv.y + tv.z*wv.z + tv.w*wv.w;
    }
    t2s[tok][j] = a;
  }
  __syncthreads();
  if (tid < 64) {
    int tok = tid >> 4, h = tid & 15;
    float a = 0.f;
    for (int d = 0; d < SIGD; ++d) a += t2s[tok][d] * head_sig[h*SIGD + d];
    ss[tok][h] = a;
  }
  __syncthreads();
  if (tid < 64) {
    int tok = tid >> 4, h = tid & 15;
    float sv = ss[tok][h];
    int cnt = 0;
    #pragma unroll
    for (int j = 0; j < NHEAD; ++j) cnt += (ss[tok][j] > sv) ? 1 : 0;
    // cnt<KEEP  <=>  s[h] >= 12th-largest (matches ref incl. ties)
    int gt = tok0 + tok;
    int s = gt >> 1, b = gt & 1;             // token row = s*B + b
    maskbuf[((size_t)(b*NHEAD + h)) * S_LEN + s] = (cnt < KEEP) ? 1.0f : 0.0f;
  }
}

// Flash attention, one block per (b,h, 64-row q-tile). Q pre-scaled.
// LDS tiles padded to 72 shorts/row (144 B): ds_read_b128 bank incidences
// spread 8/bank (floor) instead of 16 on half the banks at 128 B stride.
// Writes gated O (bf16) IN-PLACE over the Q buffer.
__global__ __launch_bounds__(256) void flash_attn(
    short* QpOg,                               // read Q, write gated O
    const short* __restrict__ Kp, const short* __restrict__ Vp,
    const float* __restrict__ maskbuf)
{
  __shared__ short Qs[64][72];
  __shared__ short Ks[64][72];
  __shared__ short Vt[64][72];      // transposed: Vt[d][n]
  __shared__ short Ps[4][16][72];   // per-wave P tile
  const int bh = blockIdx.x;
  const int b = bh >> 4, h = bh & 15;
  const int q0 = blockIdx.y * 64;
  const int tid = threadIdx.x;
  const int wave = tid >> 6, lane = tid & 63;
  const int quad = lane >> 4, l16 = lane & 15;
  const size_t colbase = (size_t)b * EDIM + h * DHEAD;
  const size_t rstride = (size_t)BATCH * EDIM;   // 2048
  {
    int r = tid >> 2, d0 = (tid & 3) * 16;
    const short* src = QpOg + (size_t)(q0 + r) * rstride + colbase + d0;
    *(uint4*)&Qs[r][d0]     = *(const uint4*)src;
    *(uint4*)&Qs[r][d0 + 8] = *(const uint4*)(src + 8);
  }
  float m_i[4], l_i[4];
  f32x4 oacc[4];
  #pragma unroll
  for (int r = 0; r < 4; ++r) { m_i[r] = -1e30f; l_i[r] = 0.f; }
  #pragma unroll
  for (int dt = 0; dt < 4; ++dt) oacc[dt] = f32x4{0.f, 0.f, 0.f, 0.f};

  for (int kv0 = 0; kv0 < S_LEN; kv0 += 64) {
    __syncthreads();
    {
      int r = tid >> 2, d0 = (tid & 3) * 16;
      const short* src = Kp + (size_t)(kv0 + r) * rstride + colbase + d0;
      *(uint4*)&Ks[r][d0]     = *(const uint4*)src;
      *(uint4*)&Ks[r][d0 + 8] = *(const uint4*)(src + 8);
    }
    #pragma unroll
    for (int it = 0; it < 2; ++it) {
      int idx = tid + it * 256;
      int n = idx >> 3, d0 = (idx & 7) * 8;
      uint4 vv = *(const uint4*)(Vp + (size_t)(kv0 + n) * rstride + colbase + d0);
      const short* vp = (const short*)&vv;
      #pragma unroll
      for (int u = 0; u < 8; ++u) Vt[d0 + u][n] = vp[u];
    }
    __syncthreads();
    f32x4 sacc[4] = {};
    #pragma unroll
    for (int ks = 0; ks < 2; ++ks) {
      bf16x8 a = *(const bf16x8*)&Qs[wave*16 + l16][ks*32 + quad*8];
      #pragma unroll
      for (int c = 0; c < 4; ++c) {
        bf16x8 bb = *(const bf16x8*)&Ks[c*16 + l16][ks*32 + quad*8];
        sacc[c] = __builtin_amdgcn_mfma_f32_16x16x32_bf16(a, bb, sacc[c], 0, 0, 0);
      }
    }
    float p[4][4];
    #pragma unroll
    for (int r = 0; r < 4; ++r) {
      float vmax = fmaxf(fmaxf(sacc[0][r], sacc[1][r]), fmaxf(sacc[2][r], sacc[3][r]));
      #pragma unroll
      for (int off = 1; off < 16; off <<= 1) vmax = fmaxf(vmax, __shfl_xor(vmax, off, 64));
      float mnew = fmaxf(m_i[r], vmax);
      float alpha = __expf(m_i[r] - mnew);
      float rsum = 0.f;
      #pragma unroll
      for (int c = 0; c < 4; ++c) {
        float pv = bf2f(f2bf(__expf(sacc[c][r] - mnew)));  // keep l consistent with bf16 P
        p[c][r] = pv; rsum += pv;
      }
      #pragma unroll
      for (int off = 1; off < 16; off <<= 1) rsum += __shfl_xor(rsum, off, 64);
      l_i[r] = l_i[r] * alpha + rsum;
      m_i[r] = mnew;
      #pragma unroll
      for (int dt = 0; dt < 4; ++dt) oacc[dt][r] *= alpha;
    }
    #pragma unroll
    for (int c = 0; c < 4; ++c)
      #pragma unroll
      for (int r = 0; r < 4; ++r)
        Ps[wave][quad*4 + r][c*16 + l16] = f2bf(p[c][r]);
    __syncthreads();
    #pragma unroll
    for (int ks = 0; ks < 2; ++ks) {
      bf16x8 a = *(const bf16x8*)&Ps[wave][l16][ks*32 + quad*8];
      #pragma unroll
      for (int dt = 0; dt < 4; ++dt) {
        bf16x8 bb = *(const bf16x8*)&Vt[dt*16 + l16][ks*32 + quad*8];
        oacc[dt] = __builtin_amdgcn_mfma_f32_16x16x32_bf16(a, bb, oacc[dt], 0, 0, 0);
      }
    }
  }
  #pragma unroll
  for (int r = 0; r < 4; ++r) {
    int s = q0 + wave*16 + quad*4 + r;
    float mk = maskbuf[((size_t)(b*NHEAD + h)) * S_LEN + s];
    float scale = mk / l_i[r];
    short* dst = QpOg + (size_t)s * rstride + colbase;
    #pragma unroll
    for (int dt = 0; dt < 4; ++dt)
      dst[dt*16 + l16] = f2bf(oacc[dt][r] * scale);
  }
}

extern "C" void kernel_launch(void* const* d_in, const int* in_sizes, int n_in,
                              void* d_out, int out_size, void* d_ws, size_t ws_size,
                              hipStream_t stream)
{
  const float* query   = (const float*)d_in[0];
  const float* q_w     = (const float*)d_in[1];
  const float* q_b     = (const float*)d_in[2];
  const float* k_w     = (const float*)d_in[3];
  const float* k_b     = (const float*)d_in[4];
  const float* v_w     = (const float*)d_in[5];
  const float* v_b     = (const float*)d_in[6];
  const float* out_w   = (const float*)d_in[7];
  const float* out_b   = (const float*)d_in[8];
  const float* inf1_w  = (const float*)d_in[9];
  const float* inf1_b  = (const float*)d_in[10];
  const float* inf2_w  = (const float*)d_in[11];
  const float* inf2_b  = (const float*)d_in[12];
  const float* head_sig= (const float*)d_in[13];

  // ws: 32 MB total (same footprint that passed in R2).
  char* ws = (char*)d_ws;
  short* qh = (short*)(ws);                        // 8 MB, live until QKV gemms done
  short* ql = (short*)(ws + (size_t)( 8u<<20));    // 8 MB, dead after gemm_t1
  short* Qp = (short*)(ws + (size_t)( 8u<<20));    // reuses ql slot (becomes gated O)
  short* Kp = (short*)(ws + (size_t)(16u<<20));    // 8 MB
  short* Vp = (short*)(ws + (size_t)(24u<<20));    // 8 MB
  // d_out (16 MB fp32) doubles as mask-phase scratch; fully overwritten at the end.
  char* ob = (char*)d_out;
  float* T1      = (float*)(ob);                      // 8 MB  relu(t1) fp32
  short* w1h     = (short*)(ob + (size_t)( 8u<<20));  // 1 MB
  short* w1l     = (short*)(ob + (size_t)( 9u<<20));  // 1 MB
  float* maskbuf = (float*)(ob + (size_t)(10u<<20));  // 256 KB
  float* out     = (float*)d_out;

  dim3 blk(256);
  // ---- mask path (uses d_out as scratch) ----
  cvt_split_kernel<<<dim3(4096), blk, 0, stream>>>(query,  qh,  ql);
  cvt_split_kernel<<<dim3(512),  blk, 0, stream>>>(inf1_w, w1h, w1l);
  gemm_t1<<<dim3(64, 8), blk, 0, stream>>>(qh, ql, w1h, w1l, inf1_b, T1);
  head_mask_kernel<<<dim3(1024), blk, 0, stream>>>(T1, inf2_w, inf2_b, head_sig, maskbuf);
  // ---- QKV projections (ql slot is dead; Qp overwrites it) ----
  gemm_aw<0><<<dim3(64,16), blk, 0, stream>>>(qh, q_w, q_b, (void*)Qp);
  gemm_aw<1><<<dim3(64,16), blk, 0, stream>>>(qh, k_w, k_b, (void*)Kp);
  gemm_aw<1><<<dim3(64,16), blk, 0, stream>>>(qh, v_w, v_b, (void*)Vp);
  // ---- attention + gating (O replaces Qp) ----
  flash_attn<<<dim3(32, 32), blk, 0, stream>>>(Qp, Kp, Vp, maskbuf);
  // ---- out projection: overwrites all of d_out (scratch now dead) ----
  gemm_aw<3><<<dim3(64,16), blk, 0, stream>>>(Qp, out_w, out_b, (void*)out);
}

// Round 4
// 409.464 us; speedup vs baseline: 1.6650x; 1.1627x over previous
//
#include <hip/hip_runtime.h>
#include <hip/hip_bf16.h>

#define S_LEN 2048
#define BATCH 2
#define EDIM 1024
#define NHEAD 16
#define DHEAD 64
#define HIDDEN 512
#define SIGD 64
#define KEEP 12           // NUM_HEADS - INACTIVE

typedef __attribute__((ext_vector_type(8))) short bf16x8;
typedef __attribute__((ext_vector_type(4))) float f32x4;

static __device__ __forceinline__ float bf2f(short s) {
  unsigned int u = ((unsigned int)(unsigned short)s) << 16;
  float f; __builtin_memcpy(&f, &u, 4); return f;
}
static __device__ __forceinline__ short f2bf(float f) {
  unsigned int u; __builtin_memcpy(&u, &f, 4);
  u += 0x7fffu + ((u >> 16) & 1u);   // round-to-nearest-even
  return (short)(u >> 16);
}

// DPP all-reduce across the 16 lanes of a DPP row (= our quad group).
template<int CTRL>
static __device__ __forceinline__ float dpp_movf(float x) {
  return __builtin_bit_cast(float, __builtin_amdgcn_update_dpp(
      0, __builtin_bit_cast(int, x), CTRL, 0xF, 0xF, true));
}
static __device__ __forceinline__ float row_max16(float v) {
  v = fmaxf(v, dpp_movf<0x128>(v));   // row_ror:8
  v = fmaxf(v, dpp_movf<0x124>(v));   // row_ror:4
  v = fmaxf(v, dpp_movf<0x122>(v));   // row_ror:2
  v = fmaxf(v, dpp_movf<0x121>(v));   // row_ror:1
  return v;
}
static __device__ __forceinline__ float row_sum16(float v) {
  v += dpp_movf<0x128>(v);
  v += dpp_movf<0x124>(v);
  v += dpp_movf<0x122>(v);
  v += dpp_movf<0x121>(v);
  return v;
}

// fp32 -> (hi bf16, lo bf16) split; 4 elems/thread.
__global__ __launch_bounds__(256) void cvt_split_kernel(
    const float* __restrict__ in, short* __restrict__ outh, short* __restrict__ outl)
{
  int i = (blockIdx.x * 256 + threadIdx.x) * 4;
  float4 f = *(const float4*)(in + i);
  union { short s[4]; uint2 v; } uh, ul;
  float x[4] = {f.x, f.y, f.z, f.w};
  #pragma unroll
  for (int u = 0; u < 4; ++u) {
    short h = f2bf(x[u]);
    uh.s[u] = h;
    ul.s[u] = f2bf(x[u] - bf2f(h));
  }
  *(uint2*)(outh + i) = uh.v;
  *(uint2*)(outl + i) = ul.v;
}

// C = A @ W^T + bias.  A: M x 1024 bf16 row-major. W: N x 1024 FP32 row-major
// (converted to bf16 inline during staging). bias fp32.
// MODE 0: (acc+b)*0.125 -> bf16. MODE 1: acc+b -> bf16. MODE 3: acc+b -> fp32.
template<int MODE>
__global__ __launch_bounds__(256) void gemm_aw(
    const short* __restrict__ A, const float* __restrict__ W,
    const float* __restrict__ bias, void* __restrict__ outv)
{
  const int K = EDIM;
  __shared__ short As[64][32];
  __shared__ short Bs[64][32];
  const int tid  = threadIdx.x;
  const int wave = tid >> 6;
  const int lane = tid & 63;
  const int quad = lane >> 4, l16 = lane & 15;
  const int row0 = blockIdx.x * 64, col0 = blockIdx.y * 64;
  const int lr = tid >> 2, lc = (tid & 3) * 8;
  f32x4 acc0 = {}, acc1 = {}, acc2 = {}, acc3 = {};
  const size_t aoff = (size_t)(row0 + lr) * K + lc;
  const size_t woff = (size_t)(col0 + lr) * K + lc;
  for (int k0 = 0; k0 < K; k0 += 32) {
    __syncthreads();
    *(uint4*)(&As[lr][lc]) = *(const uint4*)(A + aoff + k0);
    {
      const float* src = W + woff + k0;
      float4 f0 = *(const float4*)src;
      float4 f1 = *(const float4*)(src + 4);
      union { short s[8]; uint4 v; } u;
      u.s[0] = f2bf(f0.x); u.s[1] = f2bf(f0.y); u.s[2] = f2bf(f0.z); u.s[3] = f2bf(f0.w);
      u.s[4] = f2bf(f1.x); u.s[5] = f2bf(f1.y); u.s[6] = f2bf(f1.z); u.s[7] = f2bf(f1.w);
      *(uint4*)(&Bs[lr][lc]) = u.v;
    }
    __syncthreads();
    bf16x8 a  = *(const bf16x8*)(&As[wave*16 + l16][quad*8]);
    bf16x8 b0 = *(const bf16x8*)(&Bs[0*16 + l16][quad*8]);
    bf16x8 b1 = *(const bf16x8*)(&Bs[1*16 + l16][quad*8]);
    bf16x8 b2 = *(const bf16x8*)(&Bs[2*16 + l16][quad*8]);
    bf16x8 b3 = *(const bf16x8*)(&Bs[3*16 + l16][quad*8]);
    acc0 = __builtin_amdgcn_mfma_f32_16x16x32_bf16(a, b0, acc0, 0, 0, 0);
    acc1 = __builtin_amdgcn_mfma_f32_16x16x32_bf16(a, b1, acc1, 0, 0, 0);
    acc2 = __builtin_amdgcn_mfma_f32_16x16x32_bf16(a, b2, acc2, 0, 0, 0);
    acc3 = __builtin_amdgcn_mfma_f32_16x16x32_bf16(a, b3, acc3, 0, 0, 0);
  }
  f32x4 accs[4] = {acc0, acc1, acc2, acc3};
  #pragma unroll
  for (int c = 0; c < 4; ++c) {
    int col = col0 + c*16 + l16;
    float bv = bias[col];
    #pragma unroll
    for (int r = 0; r < 4; ++r) {
      int row = row0 + wave*16 + quad*4 + r;
      float v = accs[c][r] + bv;
      if (MODE == 0) v *= 0.125f;                 // D^-0.5 = 64^-0.5
      if constexpr (MODE == 3) {
        ((float*)outv)[(size_t)row * EDIM + col] = v;
      } else {
        ((short*)outv)[(size_t)row * EDIM + col] = f2bf(v);
      }
    }
  }
}

// t1 = relu(query @ inf1_w^T + b) with hi/lo-split inputs (3 MFMAs ~ fp32-exact).
__global__ __launch_bounds__(256) void gemm_t1(
    const short* __restrict__ Agh, const short* __restrict__ Agl,
    const short* __restrict__ Bgh, const short* __restrict__ Bgl,
    const float* __restrict__ bias, float* __restrict__ T1)
{
  const int K = EDIM;
  __shared__ short Ah[64][32], Al[64][32];
  __shared__ short Bh[64][32], Bl[64][32];
  const int tid  = threadIdx.x;
  const int wave = tid >> 6;
  const int lane = tid & 63;
  const int quad = lane >> 4, l16 = lane & 15;
  const int row0 = blockIdx.x * 64, col0 = blockIdx.y * 64;
  const int lr = tid >> 2, lc = (tid & 3) * 8;
  f32x4 acc0 = {}, acc1 = {}, acc2 = {}, acc3 = {};
  const size_t aoff = (size_t)(row0 + lr) * K + lc;
  const size_t woff = (size_t)(col0 + lr) * K + lc;
  for (int k0 = 0; k0 < K; k0 += 32) {
    __syncthreads();
    *(uint4*)(&Ah[lr][lc]) = *(const uint4*)(Agh + aoff + k0);
    *(uint4*)(&Al[lr][lc]) = *(const uint4*)(Agl + aoff + k0);
    *(uint4*)(&Bh[lr][lc]) = *(const uint4*)(Bgh + woff + k0);
    *(uint4*)(&Bl[lr][lc]) = *(const uint4*)(Bgl + woff + k0);
    __syncthreads();
    bf16x8 ah = *(const bf16x8*)(&Ah[wave*16 + l16][quad*8]);
    bf16x8 al = *(const bf16x8*)(&Al[wave*16 + l16][quad*8]);
    #pragma unroll
    for (int c = 0; c < 4; ++c) {
      bf16x8 bh = *(const bf16x8*)(&Bh[c*16 + l16][quad*8]);
      bf16x8 bl = *(const bf16x8*)(&Bl[c*16 + l16][quad*8]);
      f32x4& acc = (c == 0) ? acc0 : (c == 1) ? acc1 : (c == 2) ? acc2 : acc3;
      acc = __builtin_amdgcn_mfma_f32_16x16x32_bf16(ah, bh, acc, 0, 0, 0);
      acc = __builtin_amdgcn_mfma_f32_16x16x32_bf16(ah, bl, acc, 0, 0, 0);
      acc = __builtin_amdgcn_mfma_f32_16x16x32_bf16(al, bh, acc, 0, 0, 0);
    }
  }
  f32x4 accs[4] = {acc0, acc1, acc2, acc3};
  #pragma unroll
  for (int c = 0; c < 4; ++c) {
    int col = col0 + c*16 + l16;
    float bv = bias[col];
    #pragma unroll
    for (int r = 0; r < 4; ++r) {
      int row = row0 + wave*16 + quad*4 + r;
      T1[(size_t)row * HIDDEN + col] = fmaxf(accs[c][r] + bv, 0.0f);
    }
  }
}

// t2 = t1 @ inf2_w^T + b ; s = t2 @ head_sig^T ; mask = top-12 indicator. fp32.
__global__ __launch_bounds__(256) void head_mask_kernel(
    const float* __restrict__ T1, const float* __restrict__ inf2_w,
    const float* __restrict__ inf2_b, const float* __restrict__ head_sig,
    float* __restrict__ maskbuf)
{
  __shared__ float t1s[4][HIDDEN];
  __shared__ float t2s[4][SIGD];
  __shared__ float ss[4][NHEAD];
  const int tid = threadIdx.x;
  const int tok0 = blockIdx.x * 4;
  {
    int rtok = tid >> 6;
    int off  = (tid & 63) * 8;
    const float* src = T1 + (size_t)(tok0 + rtok) * HIDDEN + off;
    *(float4*)&t1s[rtok][off]     = *(const float4*)(src);
    *(float4*)&t1s[rtok][off + 4] = *(const float4*)(src + 4);
  }
  __syncthreads();
  {
    int tok = tid >> 6, j = tid & 63;
    const float4* w4 = (const float4*)(inf2_w + (size_t)j * HIDDEN);
    const float4* t4 = (const float4*)(&t1s[tok][0]);
    float a = inf2_b[j];
    for (int k = 0; k < HIDDEN/4; ++k) {
      float4 wv = w4[k], tv = t4[k];
      a += tv.x*wv.x + tv.y*wv.y + tv.z*wv.z + tv.w*wv.w;
    }
    t2s[tok][j] = a;
  }
  __syncthreads();
  if (tid < 64) {
    int tok = tid >> 4, h = tid & 15;
    float a = 0.f;
    for (int d = 0; d < SIGD; ++d) a += t2s[tok][d] * head_sig[h*SIGD + d];
    ss[tok][h] = a;
  }
  __syncthreads();
  if (tid < 64) {
    int tok = tid >> 4, h = tid & 15;
    float sv = ss[tok][h];
    int cnt = 0;
    #pragma unroll
    for (int j = 0; j < NHEAD; ++j) cnt += (ss[tok][j] > sv) ? 1 : 0;
    int gt = tok0 + tok;
    int s = gt >> 1, b = gt & 1;             // token row = s*B + b
    maskbuf[((size_t)(b*NHEAD + h)) * S_LEN + s] = (cnt < KEEP) ? 1.0f : 0.0f;
  }
}

// Flash attention. Block = (b,h, 64 q-rows); kv-tile = 128.
// - Q fragments hoisted to registers (LDS staging region reused for Ps).
// - Vt stored transposed with XOR swizzle: phys group = (n>>3) ^ ((d>>3)^(d&7)).
//   Transpose b16 stores conflict-free; b128 reads at the 8-incidence floor.
// - Softmax reductions via DPP row_ror (16-lane rows == quad groups), no LDS.
// - 2 barriers per kv-iter; Ps is per-wave (wave-lockstep + lgkmcnt only).
__global__ __launch_bounds__(256) void flash_attn(
    short* QpOg, const short* __restrict__ Kp, const short* __restrict__ Vp,
    const float* __restrict__ maskbuf)
{
  __shared__ __attribute__((aligned(16))) short Ks[128][72];   // 18432 B
  __shared__ __attribute__((aligned(16))) short Vt[64*128];    // 16384 B
  __shared__ __attribute__((aligned(16))) short uni[8704];     // Qstage 64x72 | Ps 4x16x136
  const int bh = blockIdx.x;
  const int b = bh >> 4, h = bh & 15;
  const int q0 = blockIdx.y * 64;
  const int tid = threadIdx.x;
  const int wave = tid >> 6, lane = tid & 63;
  const int quad = lane >> 4, l16 = lane & 15;
  const size_t colbase = (size_t)b * EDIM + h * DHEAD;
  const size_t rstride = (size_t)BATCH * EDIM;   // 2048
  // stage Q (64 x 64) into uni (72-padded rows)
  {
    int r = tid >> 2, d0 = (tid & 3) * 16;
    const short* src = QpOg + (size_t)(q0 + r) * rstride + colbase + d0;
    *(uint4*)&uni[r*72 + d0]     = *(const uint4*)src;
    *(uint4*)&uni[r*72 + d0 + 8] = *(const uint4*)(src + 8);
  }
  __syncthreads();
  bf16x8 aq0 = *(const bf16x8*)&uni[(wave*16 + l16)*72 + quad*8];
  bf16x8 aq1 = *(const bf16x8*)&uni[(wave*16 + l16)*72 + 32 + quad*8];
  short* Psw = &uni[wave * 2176];        // per-wave 16 x 136

  float m_i[4], l_i[4];
  f32x4 oacc[4];
  #pragma unroll
  for (int r = 0; r < 4; ++r) { m_i[r] = -1e30f; l_i[r] = 0.f; }
  #pragma unroll
  for (int dt = 0; dt < 4; ++dt) oacc[dt] = f32x4{0.f, 0.f, 0.f, 0.f};

  for (int kv0 = 0; kv0 < S_LEN; kv0 += 128) {
    __syncthreads();                     // Ks/Vt/Ps free from previous iter
    {  // stage K: 128 rows x 64
      int r = tid >> 1, c0 = (tid & 1) * 32;
      const short* src = Kp + (size_t)(kv0 + r) * rstride + colbase + c0;
      short* dst = &Ks[r][c0];
      *(uint4*)(dst)      = *(const uint4*)(src);
      *(uint4*)(dst + 8)  = *(const uint4*)(src + 8);
      *(uint4*)(dst + 16) = *(const uint4*)(src + 16);
      *(uint4*)(dst + 24) = *(const uint4*)(src + 24);
    }
    #pragma unroll
    for (int it = 0; it < 4; ++it) {     // stage V transposed + swizzled
      int idx = tid + it * 256;
      int n = idx >> 3, d0 = (idx & 7) * 8;
      uint4 vv = *(const uint4*)(Vp + (size_t)(kv0 + n) * rstride + colbase + d0);
      const short* vp = (const short*)&vv;
      int g = n >> 3, no = n & 7, dg = idx & 7;   // dg = d0>>3
      #pragma unroll
      for (int u = 0; u < 8; ++u) {
        int pg = g ^ (dg ^ u);           // f(d) = (d>>3)^(d&7), d&7==u
        Vt[(d0 + u)*128 + pg*8 + no] = vp[u];
      }
    }
    __syncthreads();
    // S = Q K^T : 16 q-rows x 128 kv
    f32x4 sacc[8];
    #pragma unroll
    for (int c = 0; c < 8; ++c) sacc[c] = f32x4{0.f, 0.f, 0.f, 0.f};
    #pragma unroll
    for (int c = 0; c < 8; ++c) {
      bf16x8 b0 = *(const bf16x8*)&Ks[c*16 + l16][quad*8];
      bf16x8 b1 = *(const bf16x8*)&Ks[c*16 + l16][32 + quad*8];
      sacc[c] = __builtin_amdgcn_mfma_f32_16x16x32_bf16(aq0, b0, sacc[c], 0, 0, 0);
      sacc[c] = __builtin_amdgcn_mfma_f32_16x16x32_bf16(aq1, b1, sacc[c], 0, 0, 0);
    }
    // online softmax (DPP reductions within quad's 16 lanes)
    #pragma unroll
    for (int r = 0; r < 4; ++r) {
      float vmax = sacc[0][r];
      #pragma unroll
      for (int c = 1; c < 8; ++c) vmax = fmaxf(vmax, sacc[c][r]);
      vmax = row_max16(vmax);
      float mnew = fmaxf(m_i[r], vmax);
      float alpha = __expf(m_i[r] - mnew);
      float rsum = 0.f;
      #pragma unroll
      for (int c = 0; c < 8; ++c) {
        short ps = f2bf(__expf(sacc[c][r] - mnew));
        Psw[(quad*4 + r)*136 + c*16 + l16] = ps;
        rsum += bf2f(ps);                // keep l consistent with bf16 P
      }
      rsum = row_sum16(rsum);
      l_i[r] = l_i[r] * alpha + rsum;
      m_i[r] = mnew;
      #pragma unroll
      for (int dt = 0; dt < 4; ++dt) oacc[dt][r] *= alpha;
    }
    asm volatile("s_waitcnt lgkmcnt(0)" ::: "memory");   // Ps visible (same wave)
    // O += P V : k-dim = 128
    #pragma unroll
    for (int ks = 0; ks < 4; ++ks) {
      bf16x8 ap = *(const bf16x8*)&Psw[l16*136 + ks*32 + quad*8];
      #pragma unroll
      for (int dt = 0; dt < 4; ++dt) {
        int d = dt*16 + l16;
        int pg = (ks*4 + quad) ^ ((d >> 3) ^ (d & 7));
        bf16x8 bb = *(const bf16x8*)&Vt[d*128 + pg*8];
        oacc[dt] = __builtin_amdgcn_mfma_f32_16x16x32_bf16(ap, bb, oacc[dt], 0, 0, 0);
      }
    }
  }
  #pragma unroll
  for (int r = 0; r < 4; ++r) {
    int s = q0 + wave*16 + quad*4 + r;
    float mk = maskbuf[((size_t)(b*NHEAD + h)) * S_LEN + s];
    float scale = mk / l_i[r];
    short* dst = QpOg + (size_t)s * rstride + colbase;
    #pragma unroll
    for (int dt = 0; dt < 4; ++dt)
      dst[dt*16 + l16] = f2bf(oacc[dt][r] * scale);
  }
}

extern "C" void kernel_launch(void* const* d_in, const int* in_sizes, int n_in,
                              void* d_out, int out_size, void* d_ws, size_t ws_size,
                              hipStream_t stream)
{
  const float* query   = (const float*)d_in[0];
  const float* q_w     = (const float*)d_in[1];
  const float* q_b     = (const float*)d_in[2];
  const float* k_w     = (const float*)d_in[3];
  const float* k_b     = (const float*)d_in[4];
  const float* v_w     = (const float*)d_in[5];
  const float* v_b     = (const float*)d_in[6];
  const float* out_w   = (const float*)d_in[7];
  const float* out_b   = (const float*)d_in[8];
  const float* inf1_w  = (const float*)d_in[9];
  const float* inf1_b  = (const float*)d_in[10];
  const float* inf2_w  = (const float*)d_in[11];
  const float* inf2_b  = (const float*)d_in[12];
  const float* head_sig= (const float*)d_in[13];

  // ws: 32 MB total.
  char* ws = (char*)d_ws;
  short* qh = (short*)(ws);                        // 8 MB, live until QKV gemms done
  short* ql = (short*)(ws + (size_t)( 8u<<20));    // 8 MB, dead after gemm_t1
  short* Qp = (short*)(ws + (size_t)( 8u<<20));    // reuses ql slot (becomes gated O)
  short* Kp = (short*)(ws + (size_t)(16u<<20));    // 8 MB
  short* Vp = (short*)(ws + (size_t)(24u<<20));    // 8 MB
  // d_out (16 MB fp32) doubles as mask-phase scratch; fully overwritten at the end.
  char* ob = (char*)d_out;
  float* T1      = (float*)(ob);                      // 8 MB  relu(t1) fp32
  short* w1h     = (short*)(ob + (size_t)( 8u<<20));  // 1 MB
  short* w1l     = (short*)(ob + (size_t)( 9u<<20));  // 1 MB
  float* maskbuf = (float*)(ob + (size_t)(10u<<20));  // 256 KB
  float* out     = (float*)d_out;

  dim3 blk(256);
  // ---- mask path (uses d_out as scratch) ----
  cvt_split_kernel<<<dim3(4096), blk, 0, stream>>>(query,  qh,  ql);
  cvt_split_kernel<<<dim3(512),  blk, 0, stream>>>(inf1_w, w1h, w1l);
  gemm_t1<<<dim3(64, 8), blk, 0, stream>>>(qh, ql, w1h, w1l, inf1_b, T1);
  head_mask_kernel<<<dim3(1024), blk, 0, stream>>>(T1, inf2_w, inf2_b, head_sig, maskbuf);
  // ---- QKV projections (ql slot is dead; Qp overwrites it) ----
  gemm_aw<0><<<dim3(64,16), blk, 0, stream>>>(qh, q_w, q_b, (void*)Qp);
  gemm_aw<1><<<dim3(64,16), blk, 0, stream>>>(qh, k_w, k_b, (void*)Kp);
  gemm_aw<1><<<dim3(64,16), blk, 0, stream>>>(qh, v_w, v_b, (void*)Vp);
  // ---- attention + gating (O replaces Qp) ----
  flash_attn<<<dim3(32, 32), blk, 0, stream>>>(Qp, Kp, Vp, maskbuf);
  // ---- out projection: overwrites all of d_out (scratch now dead) ----
  gemm_aw<3><<<dim3(64,16), blk, 0, stream>>>(Qp, out_w, out_b, (void*)out);
}

// Round 5
// 378.449 us; speedup vs baseline: 1.8014x; 1.0820x over previous
//
#include <hip/hip_runtime.h>
#include <hip/hip_bf16.h>

#define S_LEN 2048
#define BATCH 2
#define EDIM 1024
#define NHEAD 16
#define DHEAD 64
#define HIDDEN 512
#define SIGD 64
#define KEEP 12           // NUM_HEADS - INACTIVE

typedef __attribute__((ext_vector_type(8))) short bf16x8;
typedef __attribute__((ext_vector_type(4))) float f32x4;

static __device__ __forceinline__ float bf2f(short s) {
  unsigned int u = ((unsigned int)(unsigned short)s) << 16;
  float f; __builtin_memcpy(&f, &u, 4); return f;
}
static __device__ __forceinline__ short f2bf(float f) {
  unsigned int u; __builtin_memcpy(&u, &f, 4);
  u += 0x7fffu + ((u >> 16) & 1u);   // round-to-nearest-even
  return (short)(u >> 16);
}

// async global->LDS, 16B per lane. LDS dest must be wave-uniform base;
// HW writes base + lane*16 (guide §5, m97/m104).
static __device__ __forceinline__ void gl_lds16(const short* g, short* l) {
  __builtin_amdgcn_global_load_lds(
      (const __attribute__((address_space(1))) unsigned int*)g,
      (__attribute__((address_space(3))) unsigned int*)l, 16, 0, 0);
}

// DPP all-reduce across the 16 lanes of a DPP row (= our quad group).
template<int CTRL>
static __device__ __forceinline__ float dpp_movf(float x) {
  return __builtin_bit_cast(float, __builtin_amdgcn_update_dpp(
      0, __builtin_bit_cast(int, x), CTRL, 0xF, 0xF, true));
}
static __device__ __forceinline__ float row_max16(float v) {
  v = fmaxf(v, dpp_movf<0x128>(v));   // row_ror:8
  v = fmaxf(v, dpp_movf<0x124>(v));   // row_ror:4
  v = fmaxf(v, dpp_movf<0x122>(v));   // row_ror:2
  v = fmaxf(v, dpp_movf<0x121>(v));   // row_ror:1
  return v;
}
static __device__ __forceinline__ float row_sum16(float v) {
  v += dpp_movf<0x128>(v);
  v += dpp_movf<0x124>(v);
  v += dpp_movf<0x122>(v);
  v += dpp_movf<0x121>(v);
  return v;
}

// fp32 -> bf16; 4 elems/thread.
__global__ __launch_bounds__(256) void cvt_bf16_kernel(
    const float* __restrict__ in, short* __restrict__ out)
{
  int i = (blockIdx.x * 256 + threadIdx.x) * 4;
  float4 f = *(const float4*)(in + i);
  union { short s[4]; uint2 v; } u;
  u.s[0] = f2bf(f.x); u.s[1] = f2bf(f.y); u.s[2] = f2bf(f.z); u.s[3] = f2bf(f.w);
  *(uint2*)(out + i) = u.v;
}

// fp32 -> (hi bf16, lo bf16) split; 4 elems/thread.
__global__ __launch_bounds__(256) void cvt_split_kernel(
    const float* __restrict__ in, short* __restrict__ outh, short* __restrict__ outl)
{
  int i = (blockIdx.x * 256 + threadIdx.x) * 4;
  float4 f = *(const float4*)(in + i);
  union { short s[4]; uint2 v; } uh, ul;
  float x[4] = {f.x, f.y, f.z, f.w};
  #pragma unroll
  for (int u = 0; u < 4; ++u) {
    short h = f2bf(x[u]);
    uh.s[u] = h;
    ul.s[u] = f2bf(x[u] - bf2f(h));
  }
  *(uint2*)(outh + i) = uh.v;
  *(uint2*)(outl + i) = ul.v;
}

// m97-style 128x128 GEMM body: C = A @ B^T + bias. A,B bf16 (K=1024), BK=32,
// global_load_lds staging, 2-barrier K-loop, frag-prefetch before next stage.
template<bool F32OUT>
static __device__ __forceinline__ void gemm128_body(
    const short* __restrict__ A, const short* __restrict__ B,
    const float* __restrict__ bias, void* __restrict__ outv,
    int row0, int col0, float scale)
{
  __shared__ __attribute__((aligned(16))) short As[128*32];
  __shared__ __attribute__((aligned(16))) short Bs[128*32];
  const int tid  = threadIdx.x;
  const int wave = tid >> 6, lane = tid & 63;
  const int quad = lane >> 4, l16 = lane & 15;
  const int wr = wave >> 1, wc = wave & 1;
  const int lr = lane >> 2, lc8 = (lane & 3) * 8;

  const short* gA = A + (size_t)(row0 + wave*16 + lr) * EDIM + lc8;
  const short* gB = B + (size_t)(col0 + wave*16 + lr) * EDIM + lc8;
  short* lA = As + wave*512;          // + lane*16B written by HW
  short* lB = Bs + wave*512;

  f32x4 acc[4][4] = {};
  gl_lds16(gA, lA);  gl_lds16(gA + 64*EDIM, lA + 64*32);
  gl_lds16(gB, lB);  gl_lds16(gB + 64*EDIM, lB + 64*32);

  for (int k0 = 0; k0 < EDIM; k0 += 32) {
    __syncthreads();                  // staging done (vmcnt drained at barrier)
    bf16x8 af[4], bfr[4];
    #pragma unroll
    for (int i = 0; i < 4; ++i)
      af[i] = *(const bf16x8*)&As[(wr*64 + i*16 + l16)*32 + quad*8];
    #pragma unroll
    for (int j = 0; j < 4; ++j)
      bfr[j] = *(const bf16x8*)&Bs[(wc*64 + j*16 + l16)*32 + quad*8];
    __syncthreads();                  // all waves read LDS (lgkm drained)
    if (k0 + 32 < EDIM) {
      const short* gA2 = gA + k0 + 32;
      const short* gB2 = gB + k0 + 32;
      gl_lds16(gA2, lA);  gl_lds16(gA2 + 64*EDIM, lA + 64*32);
      gl_lds16(gB2, lB);  gl_lds16(gB2 + 64*EDIM, lB + 64*32);
    }
    #pragma unroll
    for (int i = 0; i < 4; ++i)
      #pragma unroll
      for (int j = 0; j < 4; ++j)
        acc[i][j] = __builtin_amdgcn_mfma_f32_16x16x32_bf16(af[i], bfr[j], acc[i][j], 0, 0, 0);
  }
  #pragma unroll
  for (int j = 0; j < 4; ++j) {
    int col = col0 + wc*64 + j*16 + l16;
    float bv = bias[col];
    #pragma unroll
    for (int i = 0; i < 4; ++i) {
      int rowb = row0 + wr*64 + i*16 + quad*4;
      #pragma unroll
      for (int r = 0; r < 4; ++r) {
        float v = (acc[i][j][r] + bv) * scale;
        if constexpr (F32OUT) {
          ((float*)outv)[(size_t)(rowb + r) * EDIM + col] = v;
        } else {
          ((short*)outv)[(size_t)(rowb + r) * EDIM + col] = f2bf(v);
        }
      }
    }
  }
}

// Fused QKV projection: blockIdx.y selects matrix (0..2) and 128-col tile.
__global__ __launch_bounds__(256) void gemm_qkv(
    const short* __restrict__ A,
    const short* __restrict__ Wq, const short* __restrict__ Wk, const short* __restrict__ Wv,
    const float* __restrict__ qb, const float* __restrict__ kb, const float* __restrict__ vb,
    short* __restrict__ Qp, short* __restrict__ Kp, short* __restrict__ Vp)
{
  int mat = blockIdx.y >> 3, cb = blockIdx.y & 7;
  const short* B   = (mat == 0) ? Wq : (mat == 1) ? Wk : Wv;
  const float* bia = (mat == 0) ? qb : (mat == 1) ? kb : vb;
  short* out       = (mat == 0) ? Qp : (mat == 1) ? Kp : Vp;
  float scale      = (mat == 0) ? 0.125f : 1.0f;   // D^-0.5 on q
  gemm128_body<false>(A, B, bia, (void*)out, blockIdx.x * 128, cb * 128, scale);
}

// Out projection, fp32 out.
__global__ __launch_bounds__(256) void gemm_out(
    const short* __restrict__ A, const short* __restrict__ W,
    const float* __restrict__ bias, float* __restrict__ out)
{
  gemm128_body<true>(A, W, bias, (void*)out, blockIdx.x * 128, blockIdx.y * 128, 1.0f);
}

// t1 = relu(query @ inf1_w^T + b), hi/lo-split bf16 (fp32-accurate), m97-style.
// Tile 128 rows x 64 cols, BK=32. Waves 2x2, each 64x32 (acc[4][2], 24 MFMA/k-step).
__global__ __launch_bounds__(256) void gemm_t1_128(
    const short* __restrict__ Agh, const short* __restrict__ Agl,
    const short* __restrict__ Bgh, const short* __restrict__ Bgl,
    const float* __restrict__ bias, float* __restrict__ T1)
{
  __shared__ __attribute__((aligned(16))) short Ah[128*32], Al[128*32];
  __shared__ __attribute__((aligned(16))) short Bh[64*32],  Bl[64*32];
  const int tid  = threadIdx.x;
  const int wave = tid >> 6, lane = tid & 63;
  const int quad = lane >> 4, l16 = lane & 15;
  const int wr = wave >> 1, wc = wave & 1;
  const int lr = lane >> 2, lc8 = (lane & 3) * 8;
  const int row0 = blockIdx.x * 128, col0 = blockIdx.y * 64;

  const short* gAh = Agh + (size_t)(row0 + wave*16 + lr) * EDIM + lc8;
  const short* gAl = Agl + (size_t)(row0 + wave*16 + lr) * EDIM + lc8;
  const short* gBh = Bgh + (size_t)(col0 + wave*16 + lr) * EDIM + lc8;
  const short* gBl = Bgl + (size_t)(col0 + wave*16 + lr) * EDIM + lc8;
  short* lAh = Ah + wave*512;  short* lAl = Al + wave*512;
  short* lBh = Bh + wave*512;  short* lBl = Bl + wave*512;

  f32x4 acc[4][2] = {};
  gl_lds16(gAh, lAh);  gl_lds16(gAh + 64*EDIM, lAh + 64*32);
  gl_lds16(gAl, lAl);  gl_lds16(gAl + 64*EDIM, lAl + 64*32);
  gl_lds16(gBh, lBh);  gl_lds16(gBl, lBl);

  for (int k0 = 0; k0 < EDIM; k0 += 32) {
    __syncthreads();
    bf16x8 ah[4], al[4], bh[2], bl[2];
    #pragma unroll
    for (int i = 0; i < 4; ++i) {
      ah[i] = *(const bf16x8*)&Ah[(wr*64 + i*16 + l16)*32 + quad*8];
      al[i] = *(const bf16x8*)&Al[(wr*64 + i*16 + l16)*32 + quad*8];
    }
    #pragma unroll
    for (int j = 0; j < 2; ++j) {
      bh[j] = *(const bf16x8*)&Bh[(wc*32 + j*16 + l16)*32 + quad*8];
      bl[j] = *(const bf16x8*)&Bl[(wc*32 + j*16 + l16)*32 + quad*8];
    }
    __syncthreads();
    if (k0 + 32 < EDIM) {
      const short* p;
      p = gAh + k0 + 32;  gl_lds16(p, lAh);  gl_lds16(p + 64*EDIM, lAh + 64*32);
      p = gAl + k0 + 32;  gl_lds16(p, lAl);  gl_lds16(p + 64*EDIM, lAl + 64*32);
      gl_lds16(gBh + k0 + 32, lBh);  gl_lds16(gBl + k0 + 32, lBl);
    }
    #pragma unroll
    for (int i = 0; i < 4; ++i)
      #pragma unroll
      for (int j = 0; j < 2; ++j) {
        acc[i][j] = __builtin_amdgcn_mfma_f32_16x16x32_bf16(ah[i], bh[j], acc[i][j], 0, 0, 0);
        acc[i][j] = __builtin_amdgcn_mfma_f32_16x16x32_bf16(ah[i], bl[j], acc[i][j], 0, 0, 0);
        acc[i][j] = __builtin_amdgcn_mfma_f32_16x16x32_bf16(al[i], bh[j], acc[i][j], 0, 0, 0);
      }
  }
  #pragma unroll
  for (int j = 0; j < 2; ++j) {
    int col = col0 + wc*32 + j*16 + l16;
    float bv = bias[col];
    #pragma unroll
    for (int i = 0; i < 4; ++i) {
      int rowb = row0 + wr*64 + i*16 + quad*4;
      #pragma unroll
      for (int r = 0; r < 4; ++r)
        T1[(size_t)(rowb + r) * HIDDEN + col] = fmaxf(acc[i][j][r] + bv, 0.0f);
    }
  }
}

// t2 = t1 @ inf2_w^T + b ; s = t2 @ head_sig^T ; mask = top-12. 16 tok/block, fp32.
__global__ __launch_bounds__(256) void head_mask16(
    const float* __restrict__ T1, const float* __restrict__ inf2_w,
    const float* __restrict__ inf2_b, const float* __restrict__ head_sig,
    float* __restrict__ maskbuf)
{
  __shared__ float t1s[16][HIDDEN];     // 32 KB
  __shared__ float t2s[16][SIGD];
  __shared__ float ss[16][NHEAD];
  const int tid = threadIdx.x;
  const int tok0 = blockIdx.x * 16;
  {
    int row = tid >> 4, c0 = (tid & 15) * 32;
    const float* src = T1 + (size_t)(tok0 + row) * HIDDEN + c0;
    #pragma unroll
    for (int u = 0; u < 8; ++u)
      *(float4*)&t1s[row][c0 + u*4] = *(const float4*)(src + u*4);
  }
  __syncthreads();
  #pragma unroll
  for (int it = 0; it < 4; ++it) {
    int idx = tid + it * 256;
    int tok = idx >> 6, j = idx & 63;
    const float4* w4 = (const float4*)(inf2_w + (size_t)j * HIDDEN);
    const float4* t4 = (const float4*)(&t1s[tok][0]);
    float a = inf2_b[j];
    for (int k = 0; k < HIDDEN/4; ++k) {
      float4 wv = w4[k], tv = t4[k];
      a += tv.x*wv.x + tv.y*wv.y + tv.z*wv.z + tv.w*wv.w;
    }
    t2s[tok][j] = a;
  }
  __syncthreads();
  {
    int tok = tid >> 4, h = tid & 15;
    float a = 0.f;
    for (int d = 0; d < SIGD; ++d) a += t2s[tok][d] * head_sig[h*SIGD + d];
    ss[tok][h] = a;
  }
  __syncthreads();
  {
    int tok = tid >> 4, h = tid & 15;
    float sv = ss[tok][h];
    int cnt = 0;
    #pragma unroll
    for (int j = 0; j < NHEAD; ++j) cnt += (ss[tok][j] > sv) ? 1 : 0;
    int gt = tok0 + tok;
    int s = gt >> 1, b = gt & 1;             // token row = s*B + b
    maskbuf[((size_t)(b*NHEAD + h)) * S_LEN + s] = (cnt < KEEP) ? 1.0f : 0.0f;
  }
}

// Flash attention (unchanged from R4). Block = (b,h, 64 q-rows); kv-tile 128.
__global__ __launch_bounds__(256) void flash_attn(
    short* QpOg, const short* __restrict__ Kp, const short* __restrict__ Vp,
    const float* __restrict__ maskbuf)
{
  __shared__ __attribute__((aligned(16))) short Ks[128][72];
  __shared__ __attribute__((aligned(16))) short Vt[64*128];
  __shared__ __attribute__((aligned(16))) short uni[8704];
  const int bh = blockIdx.x;
  const int b = bh >> 4, h = bh & 15;
  const int q0 = blockIdx.y * 64;
  const int tid = threadIdx.x;
  const int wave = tid >> 6, lane = tid & 63;
  const int quad = lane >> 4, l16 = lane & 15;
  const size_t colbase = (size_t)b * EDIM + h * DHEAD;
  const size_t rstride = (size_t)BATCH * EDIM;   // 2048
  {
    int r = tid >> 2, d0 = (tid & 3) * 16;
    const short* src = QpOg + (size_t)(q0 + r) * rstride + colbase + d0;
    *(uint4*)&uni[r*72 + d0]     = *(const uint4*)src;
    *(uint4*)&uni[r*72 + d0 + 8] = *(const uint4*)(src + 8);
  }
  __syncthreads();
  bf16x8 aq0 = *(const bf16x8*)&uni[(wave*16 + l16)*72 + quad*8];
  bf16x8 aq1 = *(const bf16x8*)&uni[(wave*16 + l16)*72 + 32 + quad*8];
  short* Psw = &uni[wave * 2176];        // per-wave 16 x 136

  float m_i[4], l_i[4];
  f32x4 oacc[4];
  #pragma unroll
  for (int r = 0; r < 4; ++r) { m_i[r] = -1e30f; l_i[r] = 0.f; }
  #pragma unroll
  for (int dt = 0; dt < 4; ++dt) oacc[dt] = f32x4{0.f, 0.f, 0.f, 0.f};

  for (int kv0 = 0; kv0 < S_LEN; kv0 += 128) {
    __syncthreads();
    {  // stage K: 128 rows x 64
      int r = tid >> 1, c0 = (tid & 1) * 32;
      const short* src = Kp + (size_t)(kv0 + r) * rstride + colbase + c0;
      short* dst = &Ks[r][c0];
      *(uint4*)(dst)      = *(const uint4*)(src);
      *(uint4*)(dst + 8)  = *(const uint4*)(src + 8);
      *(uint4*)(dst + 16) = *(const uint4*)(src + 16);
      *(uint4*)(dst + 24) = *(const uint4*)(src + 24);
    }
    #pragma unroll
    for (int it = 0; it < 4; ++it) {     // stage V transposed + swizzled
      int idx = tid + it * 256;
      int n = idx >> 3, d0 = (idx & 7) * 8;
      uint4 vv = *(const uint4*)(Vp + (size_t)(kv0 + n) * rstride + colbase + d0);
      const short* vp = (const short*)&vv;
      int g = n >> 3, no = n & 7, dg = idx & 7;
      #pragma unroll
      for (int u = 0; u < 8; ++u) {
        int pg = g ^ (dg ^ u);
        Vt[(d0 + u)*128 + pg*8 + no] = vp[u];
      }
    }
    __syncthreads();
    f32x4 sacc[8];
    #pragma unroll
    for (int c = 0; c < 8; ++c) sacc[c] = f32x4{0.f, 0.f, 0.f, 0.f};
    #pragma unroll
    for (int c = 0; c < 8; ++c) {
      bf16x8 b0 = *(const bf16x8*)&Ks[c*16 + l16][quad*8];
      bf16x8 b1 = *(const bf16x8*)&Ks[c*16 + l16][32 + quad*8];
      sacc[c] = __builtin_amdgcn_mfma_f32_16x16x32_bf16(aq0, b0, sacc[c], 0, 0, 0);
      sacc[c] = __builtin_amdgcn_mfma_f32_16x16x32_bf16(aq1, b1, sacc[c], 0, 0, 0);
    }
    #pragma unroll
    for (int r = 0; r < 4; ++r) {
      float vmax = sacc[0][r];
      #pragma unroll
      for (int c = 1; c < 8; ++c) vmax = fmaxf(vmax, sacc[c][r]);
      vmax = row_max16(vmax);
      float mnew = fmaxf(m_i[r], vmax);
      float alpha = __expf(m_i[r] - mnew);
      float rsum = 0.f;
      #pragma unroll
      for (int c = 0; c < 8; ++c) {
        short ps = f2bf(__expf(sacc[c][r] - mnew));
        Psw[(quad*4 + r)*136 + c*16 + l16] = ps;
        rsum += bf2f(ps);
      }
      rsum = row_sum16(rsum);
      l_i[r] = l_i[r] * alpha + rsum;
      m_i[r] = mnew;
      #pragma unroll
      for (int dt = 0; dt < 4; ++dt) oacc[dt][r] *= alpha;
    }
    asm volatile("s_waitcnt lgkmcnt(0)" ::: "memory");
    #pragma unroll
    for (int ks = 0; ks < 4; ++ks) {
      bf16x8 ap = *(const bf16x8*)&Psw[l16*136 + ks*32 + quad*8];
      #pragma unroll
      for (int dt = 0; dt < 4; ++dt) {
        int d = dt*16 + l16;
        int pg = (ks*4 + quad) ^ ((d >> 3) ^ (d & 7));
        bf16x8 bb = *(const bf16x8*)&Vt[d*128 + pg*8];
        oacc[dt] = __builtin_amdgcn_mfma_f32_16x16x32_bf16(ap, bb, oacc[dt], 0, 0, 0);
      }
    }
  }
  #pragma unroll
  for (int r = 0; r < 4; ++r) {
    int s = q0 + wave*16 + quad*4 + r;
    float mk = maskbuf[((size_t)(b*NHEAD + h)) * S_LEN + s];
    float scale = mk / l_i[r];
    short* dst = QpOg + (size_t)s * rstride + colbase;
    #pragma unroll
    for (int dt = 0; dt < 4; ++dt)
      dst[dt*16 + l16] = f2bf(oacc[dt][r] * scale);
  }
}

extern "C" void kernel_launch(void* const* d_in, const int* in_sizes, int n_in,
                              void* d_out, int out_size, void* d_ws, size_t ws_size,
                              hipStream_t stream)
{
  const float* query   = (const float*)d_in[0];
  const float* q_w     = (const float*)d_in[1];
  const float* q_b     = (const float*)d_in[2];
  const float* k_w     = (const float*)d_in[3];
  const float* k_b     = (const float*)d_in[4];
  const float* v_w     = (const float*)d_in[5];
  const float* v_b     = (const float*)d_in[6];
  const float* out_w   = (const float*)d_in[7];
  const float* out_b   = (const float*)d_in[8];
  const float* inf1_w  = (const float*)d_in[9];
  const float* inf1_b  = (const float*)d_in[10];
  const float* inf2_w  = (const float*)d_in[11];
  const float* inf2_b  = (const float*)d_in[12];
  const float* head_sig= (const float*)d_in[13];

  // ws: 32 MB total.
  char* ws = (char*)d_ws;
  short* qh = (short*)(ws);                        // 8 MB, live until QKV gemm done
  short* ql = (short*)(ws + (size_t)( 8u<<20));    // 8 MB, dead after gemm_t1
  short* Qp = (short*)(ws + (size_t)( 8u<<20));    // reuses ql slot (becomes gated O)
  short* Kp = (short*)(ws + (size_t)(16u<<20));    // 8 MB
  short* Vp = (short*)(ws + (size_t)(24u<<20));    // 8 MB, dead after flash
  short* Wo = (short*)(ws + (size_t)(24u<<20));    // 2 MB, reuses Vp slot post-flash
  // d_out (16 MB fp32) doubles as scratch; fully overwritten by gemm_out.
  char* ob = (char*)d_out;
  float* T1      = (float*)(ob);                      // 8 MB, dead after head_mask16
  short* Wq      = (short*)(ob);                      // 2 MB, over dead T1
  short* Wk      = (short*)(ob + (size_t)( 2u<<20));  // 2 MB
  short* Wv      = (short*)(ob + (size_t)( 4u<<20));  // 2 MB
  short* w1h     = (short*)(ob + (size_t)( 8u<<20));  // 1 MB
  short* w1l     = (short*)(ob + (size_t)( 9u<<20));  // 1 MB
  float* maskbuf = (float*)(ob + (size_t)(10u<<20));  // 256 KB, live until flash
  float* out     = (float*)d_out;

  dim3 blk(256);
  // ---- mask path (d_out as scratch) ----
  cvt_split_kernel<<<dim3(4096), blk, 0, stream>>>(query,  qh,  ql);
  cvt_split_kernel<<<dim3(512),  blk, 0, stream>>>(inf1_w, w1h, w1l);
  gemm_t1_128<<<dim3(32, 8), blk, 0, stream>>>(qh, ql, w1h, w1l, inf1_b, T1);
  head_mask16<<<dim3(256), blk, 0, stream>>>(T1, inf2_w, inf2_b, head_sig, maskbuf);
  // ---- weight conversion (T1 region now dead) ----
  cvt_bf16_kernel<<<dim3(1024), blk, 0, stream>>>(q_w, Wq);
  cvt_bf16_kernel<<<dim3(1024), blk, 0, stream>>>(k_w, Wk);
  cvt_bf16_kernel<<<dim3(1024), blk, 0, stream>>>(v_w, Wv);
  // ---- fused QKV projection (ql slot dead; Qp overwrites it) ----
  gemm_qkv<<<dim3(32, 24), blk, 0, stream>>>(qh, Wq, Wk, Wv, q_b, k_b, v_b, Qp, Kp, Vp);
  // ---- attention + gating (gated O replaces Qp) ----
  flash_attn<<<dim3(32, 32), blk, 0, stream>>>(Qp, Kp, Vp, maskbuf);
  // ---- out projection (Wo into dead Vp slot; writes all of d_out) ----
  cvt_bf16_kernel<<<dim3(1024), blk, 0, stream>>>(out_w, Wo);
  gemm_out<<<dim3(32, 8), blk, 0, stream>>>(Qp, Wo, out_b, out);
}

// Round 7
// 369.279 us; speedup vs baseline: 1.8461x; 1.0248x over previous
//
#include <hip/hip_runtime.h>
#include <hip/hip_bf16.h>

#define S_LEN 2048
#define BATCH 2
#define EDIM 1024
#define NHEAD 16
#define DHEAD 64
#define HIDDEN 512
#define SIGD 64
#define KEEP 12           // NUM_HEADS - INACTIVE

typedef __attribute__((ext_vector_type(8))) short bf16x8;
typedef __attribute__((ext_vector_type(4))) float f32x4;

static __device__ __forceinline__ float bf2f(short s) {
  unsigned int u = ((unsigned int)(unsigned short)s) << 16;
  float f; __builtin_memcpy(&f, &u, 4); return f;
}
static __device__ __forceinline__ short f2bf(float f) {
  unsigned int u; __builtin_memcpy(&u, &f, 4);
  u += 0x7fffu + ((u >> 16) & 1u);   // round-to-nearest-even
  return (short)(u >> 16);
}

// async global->LDS, 16B per lane. LDS dest is wave-uniform base + lane*16.
static __device__ __forceinline__ void gl_lds16(const short* g, short* l) {
  __builtin_amdgcn_global_load_lds(
      (const __attribute__((address_space(1))) unsigned int*)g,
      (__attribute__((address_space(3))) unsigned int*)l, 16, 0, 0);
}

// DPP all-reduce across the 16 lanes of a DPP row (= our quad group).
template<int CTRL>
static __device__ __forceinline__ float dpp_movf(float x) {
  return __builtin_bit_cast(float, __builtin_amdgcn_update_dpp(
      0, __builtin_bit_cast(int, x), CTRL, 0xF, 0xF, true));
}
static __device__ __forceinline__ float row_max16(float v) {
  v = fmaxf(v, dpp_movf<0x128>(v));   // row_ror:8
  v = fmaxf(v, dpp_movf<0x124>(v));   // row_ror:4
  v = fmaxf(v, dpp_movf<0x122>(v));   // row_ror:2
  v = fmaxf(v, dpp_movf<0x121>(v));   // row_ror:1
  return v;
}
static __device__ __forceinline__ float row_sum16(float v) {
  v += dpp_movf<0x128>(v);
  v += dpp_movf<0x124>(v);
  v += dpp_movf<0x122>(v);
  v += dpp_movf<0x121>(v);
  return v;
}

// fp32 -> bf16; 4 elems/thread (single matrix).
__global__ __launch_bounds__(256) void cvt_bf16_kernel(
    const float* __restrict__ in, short* __restrict__ out)
{
  int i = (blockIdx.x * 256 + threadIdx.x) * 4;
  float4 f = *(const float4*)(in + i);
  union { short s[4]; uint2 v; } u;
  u.s[0] = f2bf(f.x); u.s[1] = f2bf(f.y); u.s[2] = f2bf(f.z); u.s[3] = f2bf(f.w);
  *(uint2*)(out + i) = u.v;
}

// fp32 -> bf16 for q_w,k_w,v_w in one launch (1M elems each; 1024 blocks each).
__global__ __launch_bounds__(256) void cvt3w_kernel(
    const float* __restrict__ qw, const float* __restrict__ kw,
    const float* __restrict__ vw,
    short* __restrict__ Wq, short* __restrict__ Wk, short* __restrict__ Wv)
{
  int blk = blockIdx.x;
  int mat = blk >> 10, sub = blk & 1023;
  const float* in = (mat == 0) ? qw : (mat == 1) ? kw : vw;
  short* out      = (mat == 0) ? Wq : (mat == 1) ? Wk : Wv;
  int i = (sub * 256 + threadIdx.x) * 4;
  float4 f = *(const float4*)(in + i);
  union { short s[4]; uint2 v; } u;
  u.s[0] = f2bf(f.x); u.s[1] = f2bf(f.y); u.s[2] = f2bf(f.z); u.s[3] = f2bf(f.w);
  *(uint2*)(out + i) = u.v;
}

// fp32 -> (hi,lo) bf16 split for query (4096 blocks) and inf1_w (512 blocks).
__global__ __launch_bounds__(256) void cvt_split_fused(
    const float* __restrict__ q,  short* __restrict__ qh,  short* __restrict__ ql,
    const float* __restrict__ w1, short* __restrict__ w1h, short* __restrict__ w1l)
{
  int blk = blockIdx.x;
  const float* in; short *oh, *ol; int i;
  if (blk < 4096) { in = q;  oh = qh;  ol = ql;  i = (blk * 256 + threadIdx.x) * 4; }
  else            { in = w1; oh = w1h; ol = w1l; i = ((blk - 4096) * 256 + threadIdx.x) * 4; }
  float4 f = *(const float4*)(in + i);
  union { short s[4]; uint2 v; } uh, ul;
  float x[4] = {f.x, f.y, f.z, f.w};
  #pragma unroll
  for (int u = 0; u < 4; ++u) {
    short h = f2bf(x[u]);
    uh.s[u] = h;
    ul.s[u] = f2bf(x[u] - bf2f(h));
  }
  *(uint2*)(oh + i) = uh.v;
  *(uint2*)(ol + i) = ul.v;
}

// m97-style 128x128 GEMM body: C = A @ B^T + bias. bf16, K=1024, BK=32.
template<bool F32OUT>
static __device__ __forceinline__ void gemm128_body(
    const short* __restrict__ A, const short* __restrict__ B,
    const float* __restrict__ bias, void* __restrict__ outv,
    int row0, int col0, float scale)
{
  __shared__ __attribute__((aligned(16))) short As[128*32];
  __shared__ __attribute__((aligned(16))) short Bs[128*32];
  const int tid  = threadIdx.x;
  const int wave = tid >> 6, lane = tid & 63;
  const int quad = lane >> 4, l16 = lane & 15;
  const int wr = wave >> 1, wc = wave & 1;
  const int lr = lane >> 2, lc8 = (lane & 3) * 8;

  const short* gA = A + (size_t)(row0 + wave*16 + lr) * EDIM + lc8;
  const short* gB = B + (size_t)(col0 + wave*16 + lr) * EDIM + lc8;
  short* lA = As + wave*512;
  short* lB = Bs + wave*512;

  f32x4 acc[4][4] = {};
  gl_lds16(gA, lA);  gl_lds16(gA + 64*EDIM, lA + 64*32);
  gl_lds16(gB, lB);  gl_lds16(gB + 64*EDIM, lB + 64*32);

  for (int k0 = 0; k0 < EDIM; k0 += 32) {
    __syncthreads();
    bf16x8 af[4], bfr[4];
    #pragma unroll
    for (int i = 0; i < 4; ++i)
      af[i] = *(const bf16x8*)&As[(wr*64 + i*16 + l16)*32 + quad*8];
    #pragma unroll
    for (int j = 0; j < 4; ++j)
      bfr[j] = *(const bf16x8*)&Bs[(wc*64 + j*16 + l16)*32 + quad*8];
    __syncthreads();
    if (k0 + 32 < EDIM) {
      const short* gA2 = gA + k0 + 32;
      const short* gB2 = gB + k0 + 32;
      gl_lds16(gA2, lA);  gl_lds16(gA2 + 64*EDIM, lA + 64*32);
      gl_lds16(gB2, lB);  gl_lds16(gB2 + 64*EDIM, lB + 64*32);
    }
    #pragma unroll
    for (int i = 0; i < 4; ++i)
      #pragma unroll
      for (int j = 0; j < 4; ++j)
        acc[i][j] = __builtin_amdgcn_mfma_f32_16x16x32_bf16(af[i], bfr[j], acc[i][j], 0, 0, 0);
  }
  #pragma unroll
  for (int j = 0; j < 4; ++j) {
    int col = col0 + wc*64 + j*16 + l16;
    float bv = bias[col];
    #pragma unroll
    for (int i = 0; i < 4; ++i) {
      int rowb = row0 + wr*64 + i*16 + quad*4;
      #pragma unroll
      for (int r = 0; r < 4; ++r) {
        float v = (acc[i][j][r] + bv) * scale;
        if constexpr (F32OUT) {
          ((float*)outv)[(size_t)(rowb + r) * EDIM + col] = v;
        } else {
          ((short*)outv)[(size_t)(rowb + r) * EDIM + col] = f2bf(v);
        }
      }
    }
  }
}

// Fused QKV projection: blockIdx.y selects matrix (0..2) and 128-col tile.
__global__ __launch_bounds__(256) void gemm_qkv(
    const short* __restrict__ A,
    const short* __restrict__ Wq, const short* __restrict__ Wk, const short* __restrict__ Wv,
    const float* __restrict__ qb, const float* __restrict__ kb, const float* __restrict__ vb,
    short* __restrict__ Qp, short* __restrict__ Kp, short* __restrict__ Vp)
{
  int mat = blockIdx.y >> 3, cb = blockIdx.y & 7;
  const short* B   = (mat == 0) ? Wq : (mat == 1) ? Wk : Wv;
  const float* bia = (mat == 0) ? qb : (mat == 1) ? kb : vb;
  short* out       = (mat == 0) ? Qp : (mat == 1) ? Kp : Vp;
  float scale      = (mat == 0) ? 0.125f : 1.0f;   // D^-0.5 on q
  gemm128_body<false>(A, B, bia, (void*)out, blockIdx.x * 128, cb * 128, scale);
}

// Out projection, fp32 out.
__global__ __launch_bounds__(256) void gemm_out(
    const short* __restrict__ A, const short* __restrict__ W,
    const float* __restrict__ bias, float* __restrict__ out)
{
  gemm128_body<true>(A, W, bias, (void*)out, blockIdx.x * 128, blockIdx.y * 128, 1.0f);
}

// t1 = relu(query @ inf1_w^T + b), hi/lo-split bf16 (fp32-accurate), m97-style.
__global__ __launch_bounds__(256) void gemm_t1_128(
    const short* __restrict__ Agh, const short* __restrict__ Agl,
    const short* __restrict__ Bgh, const short* __restrict__ Bgl,
    const float* __restrict__ bias, float* __restrict__ T1)
{
  __shared__ __attribute__((aligned(16))) short Ah[128*32], Al[128*32];
  __shared__ __attribute__((aligned(16))) short Bh[64*32],  Bl[64*32];
  const int tid  = threadIdx.x;
  const int wave = tid >> 6, lane = tid & 63;
  const int quad = lane >> 4, l16 = lane & 15;
  const int wr = wave >> 1, wc = wave & 1;
  const int lr = lane >> 2, lc8 = (lane & 3) * 8;
  const int row0 = blockIdx.x * 128, col0 = blockIdx.y * 64;

  const short* gAh = Agh + (size_t)(row0 + wave*16 + lr) * EDIM + lc8;
  const short* gAl = Agl + (size_t)(row0 + wave*16 + lr) * EDIM + lc8;
  const short* gBh = Bgh + (size_t)(col0 + wave*16 + lr) * EDIM + lc8;
  const short* gBl = Bgl + (size_t)(col0 + wave*16 + lr) * EDIM + lc8;
  short* lAh = Ah + wave*512;  short* lAl = Al + wave*512;
  short* lBh = Bh + wave*512;  short* lBl = Bl + wave*512;

  f32x4 acc[4][2] = {};
  gl_lds16(gAh, lAh);  gl_lds16(gAh + 64*EDIM, lAh + 64*32);
  gl_lds16(gAl, lAl);  gl_lds16(gAl + 64*EDIM, lAl + 64*32);
  gl_lds16(gBh, lBh);  gl_lds16(gBl, lBl);

  for (int k0 = 0; k0 < EDIM; k0 += 32) {
    __syncthreads();
    bf16x8 ah[4], al[4], bh[2], bl[2];
    #pragma unroll
    for (int i = 0; i < 4; ++i) {
      ah[i] = *(const bf16x8*)&Ah[(wr*64 + i*16 + l16)*32 + quad*8];
      al[i] = *(const bf16x8*)&Al[(wr*64 + i*16 + l16)*32 + quad*8];
    }
    #pragma unroll
    for (int j = 0; j < 2; ++j) {
      bh[j] = *(const bf16x8*)&Bh[(wc*32 + j*16 + l16)*32 + quad*8];
      bl[j] = *(const bf16x8*)&Bl[(wc*32 + j*16 + l16)*32 + quad*8];
    }
    __syncthreads();
    if (k0 + 32 < EDIM) {
      const short* p;
      p = gAh + k0 + 32;  gl_lds16(p, lAh);  gl_lds16(p + 64*EDIM, lAh + 64*32);
      p = gAl + k0 + 32;  gl_lds16(p, lAl);  gl_lds16(p + 64*EDIM, lAl + 64*32);
      gl_lds16(gBh + k0 + 32, lBh);  gl_lds16(gBl + k0 + 32, lBl);
    }
    #pragma unroll
    for (int i = 0; i < 4; ++i)
      #pragma unroll
      for (int j = 0; j < 2; ++j) {
        acc[i][j] = __builtin_amdgcn_mfma_f32_16x16x32_bf16(ah[i], bh[j], acc[i][j], 0, 0, 0);
        acc[i][j] = __builtin_amdgcn_mfma_f32_16x16x32_bf16(ah[i], bl[j], acc[i][j], 0, 0, 0);
        acc[i][j] = __builtin_amdgcn_mfma_f32_16x16x32_bf16(al[i], bh[j], acc[i][j], 0, 0, 0);
      }
  }
  #pragma unroll
  for (int j = 0; j < 2; ++j) {
    int col = col0 + wc*32 + j*16 + l16;
    float bv = bias[col];
    #pragma unroll
    for (int i = 0; i < 4; ++i) {
      int rowb = row0 + wr*64 + i*16 + quad*4;
      #pragma unroll
      for (int r = 0; r < 4; ++r)
        T1[(size_t)(rowb + r) * HIDDEN + col] = fmaxf(acc[i][j][r] + bv, 0.0f);
    }
  }
}

// t2 = t1 @ inf2_w^T + b ; s = t2 @ head_sig^T ; mask = top-12. 16 tok/block, fp32.
__global__ __launch_bounds__(256) void head_mask16(
    const float* __restrict__ T1, const float* __restrict__ inf2_w,
    const float* __restrict__ inf2_b, const float* __restrict__ head_sig,
    float* __restrict__ maskbuf)
{
  __shared__ float t1s[16][HIDDEN];     // 32 KB
  __shared__ float t2s[16][SIGD];
  __shared__ float ss[16][NHEAD];
  const int tid = threadIdx.x;
  const int tok0 = blockIdx.x * 16;
  {
    int row = tid >> 4, c0 = (tid & 15) * 32;
    const float* src = T1 + (size_t)(tok0 + row) * HIDDEN + c0;
    #pragma unroll
    for (int u = 0; u < 8; ++u)
      *(float4*)&t1s[row][c0 + u*4] = *(const float4*)(src + u*4);
  }
  __syncthreads();
  #pragma unroll
  for (int it = 0; it < 4; ++it) {
    int idx = tid + it * 256;
    int tok = idx >> 6, j = idx & 63;
    const float4* w4 = (const float4*)(inf2_w + (size_t)j * HIDDEN);
    const float4* t4 = (const float4*)(&t1s[tok][0]);
    float a = inf2_b[j];
    for (int k = 0; k < HIDDEN/4; ++k) {
      float4 wv = w4[k], tv = t4[k];
      a += tv.x*wv.x + tv.y*wv.y + tv.z*wv.z + tv.w*wv.w;
    }
    t2s[tok][j] = a;
  }
  __syncthreads();
  {
    int tok = tid >> 4, h = tid & 15;
    float a = 0.f;
    for (int d = 0; d < SIGD; ++d) a += t2s[tok][d] * head_sig[h*SIGD + d];
    ss[tok][h] = a;
  }
  __syncthreads();
  {
    int tok = tid >> 4, h = tid & 15;
    float sv = ss[tok][h];
    int cnt = 0;
    #pragma unroll
    for (int j = 0; j < NHEAD; ++j) cnt += (ss[tok][j] > sv) ? 1 : 0;
    int gt = tok0 + tok;
    int s = gt >> 1, b = gt & 1;             // token row = s*B + b
    maskbuf[((size_t)(b*NHEAD + h)) * S_LEN + s] = (cnt < KEEP) ? 1.0f : 0.0f;
  }
}

// V (token-major) -> VT[(b*16+h)*64 + d][S_LEN] via LDS tile transpose.
__global__ __launch_bounds__(256) void transpose_v(
    const short* __restrict__ Vp, short* __restrict__ VT)
{
  __shared__ short tile[64][72];
  const int s0 = blockIdx.x * 64, e0 = blockIdx.y * 64, b = blockIdx.z;
  const int t = threadIdx.x;
  {
    int sr = t >> 2, ec = (t & 3) * 16;
    const short* src = Vp + (size_t)(s0 + sr) * 2048 + b * 1024 + e0 + ec;
    *(uint4*)&tile[sr][ec]     = *(const uint4*)src;
    *(uint4*)&tile[sr][ec + 8] = *(const uint4*)(src + 8);
  }
  __syncthreads();
  {
    int er = t >> 2, sc = (t & 3) * 16;
    unsigned pack[8];
    #pragma unroll
    for (int u = 0; u < 8; ++u) {
      unsigned lo = (unsigned short)tile[sc + 2*u][er];
      unsigned hi = (unsigned short)tile[sc + 2*u + 1][er];
      pack[u] = lo | (hi << 16);
    }
    short* dst = VT + (size_t)(b * 1024 + e0 + er) * 2048 + s0 + sc;
    *(uint4*)(dst)     = *(uint4*)&pack[0];
    *(uint4*)(dst + 8) = *(uint4*)&pack[4];
  }
}

// Flash attention. Block = (b,h, 64 q-rows); kv-tile 128. V pre-transposed.
__global__ __launch_bounds__(256) void flash_attn(
    short* QpOg, const short* __restrict__ Kp, const short* __restrict__ VT,
    const float* __restrict__ maskbuf)
{
  __shared__ __attribute__((aligned(16))) short Ks[128][72];   // 18432 B
  __shared__ __attribute__((aligned(16))) short Vt[64*136];    // 17408 B (pad: free reads)
  __shared__ __attribute__((aligned(16))) short uni[8704];     // Qstage 64x72 | Ps 4x16x136
  const int bh = blockIdx.x;
  const int b = bh >> 4, h = bh & 15;
  const int q0 = blockIdx.y * 64;
  const int tid = threadIdx.x;
  const int wave = tid >> 6, lane = tid & 63;
  const int quad = lane >> 4, l16 = lane & 15;
  const size_t colbase = (size_t)b * EDIM + h * DHEAD;
  const size_t rstride = (size_t)BATCH * EDIM;   // 2048
  const short* VTbase = VT + (size_t)(bh * 64) * S_LEN;   // rows d=0..63 for this (b,h)
  {
    int r = tid >> 2, d0 = (tid & 3) * 16;
    const short* src = QpOg + (size_t)(q0 + r) * rstride + colbase + d0;
    *(uint4*)&uni[r*72 + d0]     = *(const uint4*)src;
    *(uint4*)&uni[r*72 + d0 + 8] = *(const uint4*)(src + 8);
  }
  __syncthreads();
  bf16x8 aq0 = *(const bf16x8*)&uni[(wave*16 + l16)*72 + quad*8];
  bf16x8 aq1 = *(const bf16x8*)&uni[(wave*16 + l16)*72 + 32 + quad*8];
  short* Psw = &uni[wave * 2176];        // per-wave 16 x 136

  float m_i[4], l_i[4];
  f32x4 oacc[4];
  #pragma unroll
  for (int r = 0; r < 4; ++r) { m_i[r] = -1e30f; l_i[r] = 0.f; }
  #pragma unroll
  for (int dt = 0; dt < 4; ++dt) oacc[dt] = f32x4{0.f, 0.f, 0.f, 0.f};

  // V staging: each thread stages a 32-short chunk of one Vt row (4 x b128).
  // Chunk rotated per row: base ≡ 4*vd + 16*(chunk&1) (mod 32) -> uniform
  // 8 incidences/bank per b128 instr (floor).
  const int vd  = tid >> 2;
  const int vcc = (((tid & 3) + vd) & 3) * 32;

  for (int kv0 = 0; kv0 < S_LEN; kv0 += 128) {
    __syncthreads();
    {  // stage K: 128 rows x 64
      int r = tid >> 1, c0 = (tid & 1) * 32;
      const short* src = Kp + (size_t)(kv0 + r) * rstride + colbase + c0;
      short* dst = &Ks[r][c0];
      *(uint4*)(dst)      = *(const uint4*)(src);
      *(uint4*)(dst + 8)  = *(const uint4*)(src + 8);
      *(uint4*)(dst + 16) = *(const uint4*)(src + 16);
      *(uint4*)(dst + 24) = *(const uint4*)(src + 24);
    }
    {  // stage V^T: 64 rows (d) x 128 cols (kv); 32 shorts/thread
      const short* src = VTbase + (size_t)vd * S_LEN + kv0 + vcc;
      short* dst = &Vt[vd*136 + vcc];
      *(uint4*)(dst)      = *(const uint4*)(src);
      *(uint4*)(dst + 8)  = *(const uint4*)(src + 8);
      *(uint4*)(dst + 16) = *(const uint4*)(src + 16);
      *(uint4*)(dst + 24) = *(const uint4*)(src + 24);
    }
    __syncthreads();
    // S = Q K^T : 16 q-rows x 128 kv
    f32x4 sacc[8];
    #pragma unroll
    for (int c = 0; c < 8; ++c) sacc[c] = f32x4{0.f, 0.f, 0.f, 0.f};
    #pragma unroll
    for (int c = 0; c < 8; ++c) {
      bf16x8 b0 = *(const bf16x8*)&Ks[c*16 + l16][quad*8];
      bf16x8 b1 = *(const bf16x8*)&Ks[c*16 + l16][32 + quad*8];
      sacc[c] = __builtin_amdgcn_mfma_f32_16x16x32_bf16(aq0, b0, sacc[c], 0, 0, 0);
      sacc[c] = __builtin_amdgcn_mfma_f32_16x16x32_bf16(aq1, b1, sacc[c], 0, 0, 0);
    }
    // online softmax; P packed via v_perm truncation (l sums the stored bits,
    // so truncation bias cancels exactly in O = PV/l).
    #pragma unroll
    for (int r = 0; r < 4; ++r) {
      float vmax = sacc[0][r];
      #pragma unroll
      for (int c = 1; c < 8; ++c) vmax = fmaxf(vmax, sacc[c][r]);
      vmax = row_max16(vmax);
      float mnew = fmaxf(m_i[r], vmax);
      float alpha = __expf(m_i[r] - mnew);
      float rsum = 0.f;
      short* prow = &Psw[(quad*4 + r)*136 + l16];
      #pragma unroll
      for (int p = 0; p < 4; ++p) {
        float ea = __expf(sacc[2*p][r]   - mnew);
        float eb = __expf(sacc[2*p+1][r] - mnew);
        unsigned pk = __builtin_amdgcn_perm(
            __builtin_bit_cast(unsigned, eb),
            __builtin_bit_cast(unsigned, ea), 0x07060302u);
        prow[(2*p)*16]     = (short)(pk & 0xffffu);
        prow[(2*p + 1)*16] = (short)(pk >> 16);
        rsum += __builtin_bit_cast(float, pk << 16);
        rsum += __builtin_bit_cast(float, pk & 0xffff0000u);
      }
      rsum = row_sum16(rsum);
      l_i[r] = l_i[r] * alpha + rsum;
      m_i[r] = mnew;
      #pragma unroll
      for (int dt = 0; dt < 4; ++dt) oacc[dt][r] *= alpha;
    }
    asm volatile("s_waitcnt lgkmcnt(0)" ::: "memory");   // Ps visible (same wave)
    // O += P V : k-dim = 128
    #pragma unroll
    for (int ks = 0; ks < 4; ++ks) {
      bf16x8 ap = *(const bf16x8*)&Psw[l16*136 + ks*32 + quad*8];
      #pragma unroll
      for (int dt = 0; dt < 4; ++dt) {
        bf16x8 bb = *(const bf16x8*)&Vt[(dt*16 + l16)*136 + ks*32 + quad*8];
        oacc[dt] = __builtin_amdgcn_mfma_f32_16x16x32_bf16(ap, bb, oacc[dt], 0, 0, 0);
      }
    }
  }
  #pragma unroll
  for (int r = 0; r < 4; ++r) {
    int s = q0 + wave*16 + quad*4 + r;
    float mk = maskbuf[((size_t)(b*NHEAD + h)) * S_LEN + s];
    float scale = mk / l_i[r];
    short* dst = QpOg + (size_t)s * rstride + colbase;
    #pragma unroll
    for (int dt = 0; dt < 4; ++dt)
      dst[dt*16 + l16] = f2bf(oacc[dt][r] * scale);
  }
}

extern "C" void kernel_launch(void* const* d_in, const int* in_sizes, int n_in,
                              void* d_out, int out_size, void* d_ws, size_t ws_size,
                              hipStream_t stream)
{
  const float* query   = (const float*)d_in[0];
  const float* q_w     = (const float*)d_in[1];
  const float* q_b     = (const float*)d_in[2];
  const float* k_w     = (const float*)d_in[3];
  const float* k_b     = (const float*)d_in[4];
  const float* v_w     = (const float*)d_in[5];
  const float* v_b     = (const float*)d_in[6];
  const float* out_w   = (const float*)d_in[7];
  const float* out_b   = (const float*)d_in[8];
  const float* inf1_w  = (const float*)d_in[9];
  const float* inf1_b  = (const float*)d_in[10];
  const float* inf2_w  = (const float*)d_in[11];
  const float* inf2_b  = (const float*)d_in[12];
  const float* head_sig= (const float*)d_in[13];

  // ws: 32 MB. [0,8) qh -> later VT; [8,16) ql -> Qp/gated O; [16,24) Kp;
  // [24,32) Vp (token-major V, dead after transpose_v) -> Wo.
  char* ws = (char*)d_ws;
  short* qh = (short*)(ws);
  short* VTb= (short*)(ws);
  short* ql = (short*)(ws + (size_t)( 8u<<20));
  short* Qp = (short*)(ws + (size_t)( 8u<<20));
  short* Kp = (short*)(ws + (size_t)(16u<<20));
  short* Vp = (short*)(ws + (size_t)(24u<<20));
  short* Wo = (short*)(ws + (size_t)(24u<<20));
  // d_out (16 MB fp32) as scratch; fully overwritten by gemm_out at the end.
  char* ob = (char*)d_out;
  float* T1      = (float*)(ob);                      // 8 MB, dead after head_mask16
  short* Wq      = (short*)(ob);                      // 2 MB over dead T1
  short* Wk      = (short*)(ob + (size_t)( 2u<<20));  // 2 MB
  short* Wv      = (short*)(ob + (size_t)( 4u<<20));  // 2 MB
  short* w1h     = (short*)(ob + (size_t)( 8u<<20));  // 1 MB
  short* w1l     = (short*)(ob + (size_t)( 9u<<20));  // 1 MB
  float* maskbuf = (float*)(ob + (size_t)(10u<<20));  // 256 KB, live until flash
  float* out     = (float*)d_out;

  dim3 blk(256);
  // ---- mask path ----
  cvt_split_fused<<<dim3(4608), blk, 0, stream>>>(query, qh, ql, inf1_w, w1h, w1l);
  gemm_t1_128<<<dim3(32, 8), blk, 0, stream>>>(qh, ql, w1h, w1l, inf1_b, T1);
  head_mask16<<<dim3(256), blk, 0, stream>>>(T1, inf2_w, inf2_b, head_sig, maskbuf);
  // ---- weights (T1 region dead) + QKV projection ----
  cvt3w_kernel<<<dim3(3072), blk, 0, stream>>>(q_w, k_w, v_w, Wq, Wk, Wv);
  gemm_qkv<<<dim3(32, 24), blk, 0, stream>>>(qh, Wq, Wk, Wv, q_b, k_b, v_b, Qp, Kp, Vp);
  // ---- V transpose into dead qh region ----
  transpose_v<<<dim3(32, 16, 2), blk, 0, stream>>>(Vp, VTb);
  // ---- attention + gating (gated O replaces Qp) ----
  flash_attn<<<dim3(32, 32), blk, 0, stream>>>(Qp, Kp, VTb, maskbuf);
  // ---- out projection (Wo into dead Vp slot; writes all of d_out) ----
  cvt_bf16_kernel<<<dim3(1024), blk, 0, stream>>>(out_w, Wo);
  gemm_out<<<dim3(32, 8), blk, 0, stream>>>(Qp, Wo, out_b, out);
}

// Round 8
// 349.874 us; speedup vs baseline: 1.9485x; 1.0555x over previous
//
#include <hip/hip_runtime.h>
#include <hip/hip_bf16.h>

#define S_LEN 2048
#define BATCH 2
#define EDIM 1024
#define NHEAD 16
#define DHEAD 64
#define HIDDEN 512
#define SIGD 64
#define KEEP 12           // NUM_HEADS - INACTIVE

typedef __attribute__((ext_vector_type(8))) short bf16x8;
typedef __attribute__((ext_vector_type(4))) float f32x4;

static __device__ __forceinline__ float bf2f(short s) {
  unsigned int u = ((unsigned int)(unsigned short)s) << 16;
  float f; __builtin_memcpy(&f, &u, 4); return f;
}
static __device__ __forceinline__ short f2bf(float f) {
  unsigned int u; __builtin_memcpy(&u, &f, 4);
  u += 0x7fffu + ((u >> 16) & 1u);   // round-to-nearest-even
  return (short)(u >> 16);
}

#if __has_builtin(__builtin_amdgcn_exp2f)
static __device__ __forceinline__ float fexp2(float x) { return __builtin_amdgcn_exp2f(x); }
#else
static __device__ __forceinline__ float fexp2(float x) { return exp2f(x); }
#endif

// async global->LDS, 16B per lane. LDS dest is wave-uniform base + lane*16.
static __device__ __forceinline__ void gl_lds16(const short* g, short* l) {
  __builtin_amdgcn_global_load_lds(
      (const __attribute__((address_space(1))) unsigned int*)g,
      (__attribute__((address_space(3))) unsigned int*)l, 16, 0, 0);
}

// DPP all-reduce across the 16 lanes of a DPP row (= our quad group).
template<int CTRL>
static __device__ __forceinline__ float dpp_movf(float x) {
  return __builtin_bit_cast(float, __builtin_amdgcn_update_dpp(
      0, __builtin_bit_cast(int, x), CTRL, 0xF, 0xF, true));
}
static __device__ __forceinline__ float row_max16(float v) {
  v = fmaxf(v, dpp_movf<0x128>(v));   // row_ror:8
  v = fmaxf(v, dpp_movf<0x124>(v));   // row_ror:4
  v = fmaxf(v, dpp_movf<0x122>(v));   // row_ror:2
  v = fmaxf(v, dpp_movf<0x121>(v));   // row_ror:1
  return v;
}
static __device__ __forceinline__ float row_sum16(float v) {
  v += dpp_movf<0x128>(v);
  v += dpp_movf<0x124>(v);
  v += dpp_movf<0x122>(v);
  v += dpp_movf<0x121>(v);
  return v;
}

// fp32 -> bf16; 4 elems/thread (single matrix).
__global__ __launch_bounds__(256) void cvt_bf16_kernel(
    const float* __restrict__ in, short* __restrict__ out)
{
  int i = (blockIdx.x * 256 + threadIdx.x) * 4;
  float4 f = *(const float4*)(in + i);
  union { short s[4]; uint2 v; } u;
  u.s[0] = f2bf(f.x); u.s[1] = f2bf(f.y); u.s[2] = f2bf(f.z); u.s[3] = f2bf(f.w);
  *(uint2*)(out + i) = u.v;
}

// fp32 -> bf16 for q_w,k_w,v_w in one launch (1M elems each; 1024 blocks each).
__global__ __launch_bounds__(256) void cvt3w_kernel(
    const float* __restrict__ qw, const float* __restrict__ kw,
    const float* __restrict__ vw,
    short* __restrict__ Wq, short* __restrict__ Wk, short* __restrict__ Wv)
{
  int blk = blockIdx.x;
  int mat = blk >> 10, sub = blk & 1023;
  const float* in = (mat == 0) ? qw : (mat == 1) ? kw : vw;
  short* out      = (mat == 0) ? Wq : (mat == 1) ? Wk : Wv;
  int i = (sub * 256 + threadIdx.x) * 4;
  float4 f = *(const float4*)(in + i);
  union { short s[4]; uint2 v; } u;
  u.s[0] = f2bf(f.x); u.s[1] = f2bf(f.y); u.s[2] = f2bf(f.z); u.s[3] = f2bf(f.w);
  *(uint2*)(out + i) = u.v;
}

// fp32 -> (hi,lo) bf16 split for query (4096 blocks) and inf1_w (512 blocks).
__global__ __launch_bounds__(256) void cvt_split_fused(
    const float* __restrict__ q,  short* __restrict__ qh,  short* __restrict__ ql,
    const float* __restrict__ w1, short* __restrict__ w1h, short* __restrict__ w1l)
{
  int blk = blockIdx.x;
  const float* in; short *oh, *ol; int i;
  if (blk < 4096) { in = q;  oh = qh;  ol = ql;  i = (blk * 256 + threadIdx.x) * 4; }
  else            { in = w1; oh = w1h; ol = w1l; i = ((blk - 4096) * 256 + threadIdx.x) * 4; }
  float4 f = *(const float4*)(in + i);
  union { short s[4]; uint2 v; } uh, ul;
  float x[4] = {f.x, f.y, f.z, f.w};
  #pragma unroll
  for (int u = 0; u < 4; ++u) {
    short h = f2bf(x[u]);
    uh.s[u] = h;
    ul.s[u] = f2bf(x[u] - bf2f(h));
  }
  *(uint2*)(oh + i) = uh.v;
  *(uint2*)(ol + i) = ul.v;
}

// m97-style 128x128 GEMM body: C = A @ B^T + bias. bf16, K=1024, BK=32.
template<bool F32OUT>
static __device__ __forceinline__ void gemm128_body(
    const short* __restrict__ A, const short* __restrict__ B,
    const float* __restrict__ bias, void* __restrict__ outv,
    int row0, int col0, float scale)
{
  __shared__ __attribute__((aligned(16))) short As[128*32];
  __shared__ __attribute__((aligned(16))) short Bs[128*32];
  const int tid  = threadIdx.x;
  const int wave = tid >> 6, lane = tid & 63;
  const int quad = lane >> 4, l16 = lane & 15;
  const int wr = wave >> 1, wc = wave & 1;
  const int lr = lane >> 2, lc8 = (lane & 3) * 8;

  const short* gA = A + (size_t)(row0 + wave*16 + lr) * EDIM + lc8;
  const short* gB = B + (size_t)(col0 + wave*16 + lr) * EDIM + lc8;
  short* lA = As + wave*512;
  short* lB = Bs + wave*512;

  f32x4 acc[4][4] = {};
  gl_lds16(gA, lA);  gl_lds16(gA + 64*EDIM, lA + 64*32);
  gl_lds16(gB, lB);  gl_lds16(gB + 64*EDIM, lB + 64*32);

  for (int k0 = 0; k0 < EDIM; k0 += 32) {
    __syncthreads();
    bf16x8 af[4], bfr[4];
    #pragma unroll
    for (int i = 0; i < 4; ++i)
      af[i] = *(const bf16x8*)&As[(wr*64 + i*16 + l16)*32 + quad*8];
    #pragma unroll
    for (int j = 0; j < 4; ++j)
      bfr[j] = *(const bf16x8*)&Bs[(wc*64 + j*16 + l16)*32 + quad*8];
    __syncthreads();
    if (k0 + 32 < EDIM) {
      const short* gA2 = gA + k0 + 32;
      const short* gB2 = gB + k0 + 32;
      gl_lds16(gA2, lA);  gl_lds16(gA2 + 64*EDIM, lA + 64*32);
      gl_lds16(gB2, lB);  gl_lds16(gB2 + 64*EDIM, lB + 64*32);
    }
    #pragma unroll
    for (int i = 0; i < 4; ++i)
      #pragma unroll
      for (int j = 0; j < 4; ++j)
        acc[i][j] = __builtin_amdgcn_mfma_f32_16x16x32_bf16(af[i], bfr[j], acc[i][j], 0, 0, 0);
  }
  #pragma unroll
  for (int j = 0; j < 4; ++j) {
    int col = col0 + wc*64 + j*16 + l16;
    float bv = bias[col];
    #pragma unroll
    for (int i = 0; i < 4; ++i) {
      int rowb = row0 + wr*64 + i*16 + quad*4;
      #pragma unroll
      for (int r = 0; r < 4; ++r) {
        float v = (acc[i][j][r] + bv) * scale;
        if constexpr (F32OUT) {
          ((float*)outv)[(size_t)(rowb + r) * EDIM + col] = v;
        } else {
          ((short*)outv)[(size_t)(rowb + r) * EDIM + col] = f2bf(v);
        }
      }
    }
  }
}

// Fused QKV projection. Q pre-scale folds D^-0.5 AND log2(e): flash softmax
// runs in the exp2 domain (v_exp_f32 is natively 2^x).
__global__ __launch_bounds__(256) void gemm_qkv(
    const short* __restrict__ A,
    const short* __restrict__ Wq, const short* __restrict__ Wk, const short* __restrict__ Wv,
    const float* __restrict__ qb, const float* __restrict__ kb, const float* __restrict__ vb,
    short* __restrict__ Qp, short* __restrict__ Kp, short* __restrict__ Vp)
{
  int mat = blockIdx.y >> 3, cb = blockIdx.y & 7;
  const short* B   = (mat == 0) ? Wq : (mat == 1) ? Wk : Wv;
  const float* bia = (mat == 0) ? qb : (mat == 1) ? kb : vb;
  short* out       = (mat == 0) ? Qp : (mat == 1) ? Kp : Vp;
  float scale      = (mat == 0) ? 0.18033688011112042f : 1.0f;  // 0.125*log2(e)
  gemm128_body<false>(A, B, bia, (void*)out, blockIdx.x * 128, cb * 128, scale);
}

// Out projection, fp32 out.
__global__ __launch_bounds__(256) void gemm_out(
    const short* __restrict__ A, const short* __restrict__ W,
    const float* __restrict__ bias, float* __restrict__ out)
{
  gemm128_body<true>(A, W, bias, (void*)out, blockIdx.x * 128, blockIdx.y * 128, 1.0f);
}

// t1 partial = query @ inf1_w^T over K-slice (hi/lo-split, fp32-accurate).
// K split 3 ways (352/352/320) -> grid (32,8,3) = 768 blocks = 3/CU.
// NO relu here; bias added by slice 0 only. head_mask16 sums + relus.
__global__ __launch_bounds__(256) void gemm_t1_128(
    const short* __restrict__ Agh, const short* __restrict__ Agl,
    const short* __restrict__ Bgh, const short* __restrict__ Bgl,
    const float* __restrict__ bias,
    float* __restrict__ P0, float* __restrict__ P1, float* __restrict__ P2)
{
  __shared__ __attribute__((aligned(16))) short Ah[128*32], Al[128*32];
  __shared__ __attribute__((aligned(16))) short Bh[64*32],  Bl[64*32];
  const int tid  = threadIdx.x;
  const int wave = tid >> 6, lane = tid & 63;
  const int quad = lane >> 4, l16 = lane & 15;
  const int wr = wave >> 1, wc = wave & 1;
  const int lr = lane >> 2, lc8 = (lane & 3) * 8;
  const int row0 = blockIdx.x * 128, col0 = blockIdx.y * 64;
  const int z = blockIdx.z;
  const int kb = z * 352, ke = (z < 2) ? kb + 352 : EDIM;
  float* P = (z == 0) ? P0 : (z == 1) ? P1 : P2;

  const short* gAh = Agh + (size_t)(row0 + wave*16 + lr) * EDIM + lc8;
  const short* gAl = Agl + (size_t)(row0 + wave*16 + lr) * EDIM + lc8;
  const short* gBh = Bgh + (size_t)(col0 + wave*16 + lr) * EDIM + lc8;
  const short* gBl = Bgl + (size_t)(col0 + wave*16 + lr) * EDIM + lc8;
  short* lAh = Ah + wave*512;  short* lAl = Al + wave*512;
  short* lBh = Bh + wave*512;  short* lBl = Bl + wave*512;

  f32x4 acc[4][2] = {};
  gl_lds16(gAh + kb, lAh);  gl_lds16(gAh + kb + 64*EDIM, lAh + 64*32);
  gl_lds16(gAl + kb, lAl);  gl_lds16(gAl + kb + 64*EDIM, lAl + 64*32);
  gl_lds16(gBh + kb, lBh);  gl_lds16(gBl + kb, lBl);

  for (int k0 = kb; k0 < ke; k0 += 32) {
    __syncthreads();
    bf16x8 ah[4], al[4], bh[2], bl[2];
    #pragma unroll
    for (int i = 0; i < 4; ++i) {
      ah[i] = *(const bf16x8*)&Ah[(wr*64 + i*16 + l16)*32 + quad*8];
      al[i] = *(const bf16x8*)&Al[(wr*64 + i*16 + l16)*32 + quad*8];
    }
    #pragma unroll
    for (int j = 0; j < 2; ++j) {
      bh[j] = *(const bf16x8*)&Bh[(wc*32 + j*16 + l16)*32 + quad*8];
      bl[j] = *(const bf16x8*)&Bl[(wc*32 + j*16 + l16)*32 + quad*8];
    }
    __syncthreads();
    if (k0 + 32 < ke) {
      const short* p;
      p = gAh + k0 + 32;  gl_lds16(p, lAh);  gl_lds16(p + 64*EDIM, lAh + 64*32);
      p = gAl + k0 + 32;  gl_lds16(p, lAl);  gl_lds16(p + 64*EDIM, lAl + 64*32);
      gl_lds16(gBh + k0 + 32, lBh);  gl_lds16(gBl + k0 + 32, lBl);
    }
    #pragma unroll
    for (int i = 0; i < 4; ++i)
      #pragma unroll
      for (int j = 0; j < 2; ++j) {
        acc[i][j] = __builtin_amdgcn_mfma_f32_16x16x32_bf16(ah[i], bh[j], acc[i][j], 0, 0, 0);
        acc[i][j] = __builtin_amdgcn_mfma_f32_16x16x32_bf16(ah[i], bl[j], acc[i][j], 0, 0, 0);
        acc[i][j] = __builtin_amdgcn_mfma_f32_16x16x32_bf16(al[i], bh[j], acc[i][j], 0, 0, 0);
      }
  }
  #pragma unroll
  for (int j = 0; j < 2; ++j) {
    int col = col0 + wc*32 + j*16 + l16;
    float bv = (z == 0) ? bias[col] : 0.0f;
    #pragma unroll
    for (int i = 0; i < 4; ++i) {
      int rowb = row0 + wr*64 + i*16 + quad*4;
      #pragma unroll
      for (int r = 0; r < 4; ++r)
        P[(size_t)(rowb + r) * HIDDEN + col] = acc[i][j][r] + bv;
    }
  }
}

// t1 = relu(P0+P1+P2); t2 = t1 @ inf2_w^T + b; s = t2 @ head_sig^T; top-12 mask.
__global__ __launch_bounds__(256) void head_mask16(
    const float* __restrict__ P0, const float* __restrict__ P1,
    const float* __restrict__ P2, const float* __restrict__ inf2_w,
    const float* __restrict__ inf2_b, const float* __restrict__ head_sig,
    float* __restrict__ maskbuf)
{
  __shared__ float t1s[16][HIDDEN];     // 32 KB
  __shared__ float t2s[16][SIGD];
  __shared__ float ss[16][NHEAD];
  const int tid = threadIdx.x;
  const int tok0 = blockIdx.x * 16;
  {
    int row = tid >> 4, c0 = (tid & 15) * 32;
    size_t base = (size_t)(tok0 + row) * HIDDEN + c0;
    #pragma unroll
    for (int u = 0; u < 8; ++u) {
      float4 a = *(const float4*)(P0 + base + u*4);
      float4 b = *(const float4*)(P1 + base + u*4);
      float4 c = *(const float4*)(P2 + base + u*4);
      float4 r;
      r.x = fmaxf(a.x + b.x + c.x, 0.0f);
      r.y = fmaxf(a.y + b.y + c.y, 0.0f);
      r.z = fmaxf(a.z + b.z + c.z, 0.0f);
      r.w = fmaxf(a.w + b.w + c.w, 0.0f);
      *(float4*)&t1s[row][c0 + u*4] = r;
    }
  }
  __syncthreads();
  #pragma unroll
  for (int it = 0; it < 4; ++it) {
    int idx = tid + it * 256;
    int tok = idx >> 6, j = idx & 63;
    const float4* w4 = (const float4*)(inf2_w + (size_t)j * HIDDEN);
    const float4* t4 = (const float4*)(&t1s[tok][0]);
    float a = inf2_b[j];
    for (int k = 0; k < HIDDEN/4; ++k) {
      float4 wv = w4[k], tv = t4[k];
      a += tv.x*wv.x + tv.y*wv.y + tv.z*wv.z + tv.w*wv.w;
    }
    t2s[tok][j] = a;
  }
  __syncthreads();
  {
    int tok = tid >> 4, h = tid & 15;
    float a = 0.f;
    for (int d = 0; d < SIGD; ++d) a += t2s[tok][d] * head_sig[h*SIGD + d];
    ss[tok][h] = a;
  }
  __syncthreads();
  {
    int tok = tid >> 4, h = tid & 15;
    float sv = ss[tok][h];
    int cnt = 0;
    #pragma unroll
    for (int j = 0; j < NHEAD; ++j) cnt += (ss[tok][j] > sv) ? 1 : 0;
    int gt = tok0 + tok;
    int s = gt >> 1, b = gt & 1;             // token row = s*B + b
    maskbuf[((size_t)(b*NHEAD + h)) * S_LEN + s] = (cnt < KEEP) ? 1.0f : 0.0f;
  }
}

// V (token-major) -> VT[(b*16+h)*64 + d][S_LEN] via LDS tile transpose.
__global__ __launch_bounds__(256) void transpose_v(
    const short* __restrict__ Vp, short* __restrict__ VT)
{
  __shared__ short tile[64][72];
  const int s0 = blockIdx.x * 64, e0 = blockIdx.y * 64, b = blockIdx.z;
  const int t = threadIdx.x;
  {
    int sr = t >> 2, ec = (t & 3) * 16;
    const short* src = Vp + (size_t)(s0 + sr) * 2048 + b * 1024 + e0 + ec;
    *(uint4*)&tile[sr][ec]     = *(const uint4*)src;
    *(uint4*)&tile[sr][ec + 8] = *(const uint4*)(src + 8);
  }
  __syncthreads();
  {
    int er = t >> 2, sc = (t & 3) * 16;
    unsigned pack[8];
    #pragma unroll
    for (int u = 0; u < 8; ++u) {
      unsigned lo = (unsigned short)tile[sc + 2*u][er];
      unsigned hi = (unsigned short)tile[sc + 2*u + 1][er];
      pack[u] = lo | (hi << 16);
    }
    short* dst = VT + (size_t)(b * 1024 + e0 + er) * 2048 + s0 + sc;
    *(uint4*)(dst)     = *(uint4*)&pack[0];
    *(uint4*)(dst + 8) = *(uint4*)&pack[4];
  }
}

// Flash attention (exp2 domain: Q carries D^-0.5*log2e). kv-tile 128.
__global__ __launch_bounds__(256) void flash_attn(
    short* QpOg, const short* __restrict__ Kp, const short* __restrict__ VT,
    const float* __restrict__ maskbuf)
{
  __shared__ __attribute__((aligned(16))) short Ks[128][72];   // 18432 B
  __shared__ __attribute__((aligned(16))) short Vt[64*136];    // 17408 B
  __shared__ __attribute__((aligned(16))) short uni[8704];     // Qstage 64x72 | Ps 4x16x136
  const int bh = blockIdx.x;
  const int b = bh >> 4, h = bh & 15;
  const int q0 = blockIdx.y * 64;
  const int tid = threadIdx.x;
  const int wave = tid >> 6, lane = tid & 63;
  const int quad = lane >> 4, l16 = lane & 15;
  const size_t colbase = (size_t)b * EDIM + h * DHEAD;
  const size_t rstride = (size_t)BATCH * EDIM;   // 2048
  const short* VTbase = VT + (size_t)(bh * 64) * S_LEN;
  {
    int r = tid >> 2, d0 = (tid & 3) * 16;
    const short* src = QpOg + (size_t)(q0 + r) * rstride + colbase + d0;
    *(uint4*)&uni[r*72 + d0]     = *(const uint4*)src;
    *(uint4*)&uni[r*72 + d0 + 8] = *(const uint4*)(src + 8);
  }
  __syncthreads();
  bf16x8 aq0 = *(const bf16x8*)&uni[(wave*16 + l16)*72 + quad*8];
  bf16x8 aq1 = *(const bf16x8*)&uni[(wave*16 + l16)*72 + 32 + quad*8];
  short* Psw = &uni[wave * 2176];        // per-wave 16 x 136

  float m_i[4], l_i[4];
  f32x4 oacc[4];
  #pragma unroll
  for (int r = 0; r < 4; ++r) { m_i[r] = -1e30f; l_i[r] = 0.f; }
  #pragma unroll
  for (int dt = 0; dt < 4; ++dt) oacc[dt] = f32x4{0.f, 0.f, 0.f, 0.f};

  const int vd  = tid >> 2;
  const int vcc = (((tid & 3) + vd) & 3) * 32;

  for (int kv0 = 0; kv0 < S_LEN; kv0 += 128) {
    __syncthreads();
    {  // stage K: 128 rows x 64
      int r = tid >> 1, c0 = (tid & 1) * 32;
      const short* src = Kp + (size_t)(kv0 + r) * rstride + colbase + c0;
      short* dst = &Ks[r][c0];
      *(uint4*)(dst)      = *(const uint4*)(src);
      *(uint4*)(dst + 8)  = *(const uint4*)(src + 8);
      *(uint4*)(dst + 16) = *(const uint4*)(src + 16);
      *(uint4*)(dst + 24) = *(const uint4*)(src + 24);
    }
    {  // stage V^T: 64 rows (d) x 128 cols (kv); 32 shorts/thread
      const short* src = VTbase + (size_t)vd * S_LEN + kv0 + vcc;
      short* dst = &Vt[vd*136 + vcc];
      *(uint4*)(dst)      = *(const uint4*)(src);
      *(uint4*)(dst + 8)  = *(const uint4*)(src + 8);
      *(uint4*)(dst + 16) = *(const uint4*)(src + 16);
      *(uint4*)(dst + 24) = *(const uint4*)(src + 24);
    }
    __syncthreads();
    // S' = Q K^T (log2 domain)
    f32x4 sacc[8];
    #pragma unroll
    for (int c = 0; c < 8; ++c) sacc[c] = f32x4{0.f, 0.f, 0.f, 0.f};
    #pragma unroll
    for (int c = 0; c < 8; ++c) {
      bf16x8 b0 = *(const bf16x8*)&Ks[c*16 + l16][quad*8];
      bf16x8 b1 = *(const bf16x8*)&Ks[c*16 + l16][32 + quad*8];
      sacc[c] = __builtin_amdgcn_mfma_f32_16x16x32_bf16(aq0, b0, sacc[c], 0, 0, 0);
      sacc[c] = __builtin_amdgcn_mfma_f32_16x16x32_bf16(aq1, b1, sacc[c], 0, 0, 0);
    }
    // online softmax via exp2; P packed via v_perm truncation
    #pragma unroll
    for (int r = 0; r < 4; ++r) {
      float vmax = sacc[0][r];
      #pragma unroll
      for (int c = 1; c < 8; ++c) vmax = fmaxf(vmax, sacc[c][r]);
      vmax = row_max16(vmax);
      float mnew = fmaxf(m_i[r], vmax);
      float alpha = fexp2(m_i[r] - mnew);
      float rsum = 0.f;
      short* prow = &Psw[(quad*4 + r)*136 + l16];
      #pragma unroll
      for (int p = 0; p < 4; ++p) {
        float ea = fexp2(sacc[2*p][r]   - mnew);
        float eb = fexp2(sacc[2*p+1][r] - mnew);
        unsigned pk = __builtin_amdgcn_perm(
            __builtin_bit_cast(unsigned, eb),
            __builtin_bit_cast(unsigned, ea), 0x07060302u);
        prow[(2*p)*16]     = (short)(pk & 0xffffu);
        prow[(2*p + 1)*16] = (short)(pk >> 16);
        rsum += ea + eb;
      }
      rsum = row_sum16(rsum);
      l_i[r] = l_i[r] * alpha + rsum;
      m_i[r] = mnew;
      #pragma unroll
      for (int dt = 0; dt < 4; ++dt) oacc[dt][r] *= alpha;
    }
    asm volatile("s_waitcnt lgkmcnt(0)" ::: "memory");   // Ps visible (same wave)
    // O += P V
    #pragma unroll
    for (int ks = 0; ks < 4; ++ks) {
      bf16x8 ap = *(const bf16x8*)&Psw[l16*136 + ks*32 + quad*8];
      #pragma unroll
      for (int dt = 0; dt < 4; ++dt) {
        bf16x8 bb = *(const bf16x8*)&Vt[(dt*16 + l16)*136 + ks*32 + quad*8];
        oacc[dt] = __builtin_amdgcn_mfma_f32_16x16x32_bf16(ap, bb, oacc[dt], 0, 0, 0);
      }
    }
  }
  #pragma unroll
  for (int r = 0; r < 4; ++r) {
    int s = q0 + wave*16 + quad*4 + r;
    float mk = maskbuf[((size_t)(b*NHEAD + h)) * S_LEN + s];
    float scale = mk / l_i[r];
    short* dst = QpOg + (size_t)s * rstride + colbase;
    #pragma unroll
    for (int dt = 0; dt < 4; ++dt)
      dst[dt*16 + l16] = f2bf(oacc[dt][r] * scale);
  }
}

extern "C" void kernel_launch(void* const* d_in, const int* in_sizes, int n_in,
                              void* d_out, int out_size, void* d_ws, size_t ws_size,
                              hipStream_t stream)
{
  const float* query   = (const float*)d_in[0];
  const float* q_w     = (const float*)d_in[1];
  const float* q_b     = (const float*)d_in[2];
  const float* k_w     = (const float*)d_in[3];
  const float* k_b     = (const float*)d_in[4];
  const float* v_w     = (const float*)d_in[5];
  const float* v_b     = (const float*)d_in[6];
  const float* out_w   = (const float*)d_in[7];
  const float* out_b   = (const float*)d_in[8];
  const float* inf1_w  = (const float*)d_in[9];
  const float* inf1_b  = (const float*)d_in[10];
  const float* inf2_w  = (const float*)d_in[11];
  const float* inf2_b  = (const float*)d_in[12];
  const float* head_sig= (const float*)d_in[13];

  // ws: 32 MB. [0,8) qh -> later VT; [8,16) ql -> Qp/gated O;
  // [16,24) t1 partial P1 -> Kp; [24,32) t1 partial P2 -> Vp -> Wo.
  char* ws = (char*)d_ws;
  short* qh = (short*)(ws);
  short* VTb= (short*)(ws);
  short* ql = (short*)(ws + (size_t)( 8u<<20));
  short* Qp = (short*)(ws + (size_t)( 8u<<20));
  float* T1p1 = (float*)(ws + (size_t)(16u<<20));
  short* Kp = (short*)(ws + (size_t)(16u<<20));
  float* T1p2 = (float*)(ws + (size_t)(24u<<20));
  short* Vp = (short*)(ws + (size_t)(24u<<20));
  short* Wo = (short*)(ws + (size_t)(24u<<20));
  // d_out (16 MB fp32) as scratch; fully overwritten by gemm_out at the end.
  char* ob = (char*)d_out;
  float* T1p0    = (float*)(ob);                      // 8 MB, dead after head_mask16
  short* Wq      = (short*)(ob);                      // 2 MB over dead P0
  short* Wk      = (short*)(ob + (size_t)( 2u<<20));  // 2 MB
  short* Wv      = (short*)(ob + (size_t)( 4u<<20));  // 2 MB
  short* w1h     = (short*)(ob + (size_t)( 8u<<20));  // 1 MB
  short* w1l     = (short*)(ob + (size_t)( 9u<<20));  // 1 MB
  float* maskbuf = (float*)(ob + (size_t)(10u<<20));  // 256 KB, live until flash
  float* out     = (float*)d_out;

  dim3 blk(256);
  // ---- mask path ----
  cvt_split_fused<<<dim3(4608), blk, 0, stream>>>(query, qh, ql, inf1_w, w1h, w1l);
  gemm_t1_128<<<dim3(32, 8, 3), blk, 0, stream>>>(qh, ql, w1h, w1l, inf1_b,
                                                  T1p0, T1p1, T1p2);
  head_mask16<<<dim3(256), blk, 0, stream>>>(T1p0, T1p1, T1p2,
                                             inf2_w, inf2_b, head_sig, maskbuf);
  // ---- weights (P0 region dead) + QKV projection ----
  cvt3w_kernel<<<dim3(3072), blk, 0, stream>>>(q_w, k_w, v_w, Wq, Wk, Wv);
  gemm_qkv<<<dim3(32, 24), blk, 0, stream>>>(qh, Wq, Wk, Wv, q_b, k_b, v_b, Qp, Kp, Vp);
  // ---- V transpose into dead qh region ----
  transpose_v<<<dim3(32, 16, 2), blk, 0, stream>>>(Vp, VTb);
  // ---- attention + gating (gated O replaces Qp) ----
  flash_attn<<<dim3(32, 32), blk, 0, stream>>>(Qp, Kp, VTb, maskbuf);
  // ---- out projection (Wo into dead Vp slot; writes all of d_out) ----
  cvt_bf16_kernel<<<dim3(1024), blk, 0, stream>>>(out_w, Wo);
  gemm_out<<<dim3(32, 8), blk, 0, stream>>>(Qp, Wo, out_b, out);
}

// Round 9
// 337.375 us; speedup vs baseline: 2.0207x; 1.0370x over previous
//
#include <hip/hip_runtime.h>
#include <hip/hip_bf16.h>

#define S_LEN 2048
#define BATCH 2
#define EDIM 1024
#define NHEAD 16
#define DHEAD 64
#define HIDDEN 512
#define SIGD 64
#define KEEP 12           // NUM_HEADS - INACTIVE

typedef __attribute__((ext_vector_type(8))) short bf16x8;
typedef __attribute__((ext_vector_type(4))) float f32x4;

static __device__ __forceinline__ float bf2f(short s) {
  unsigned int u = ((unsigned int)(unsigned short)s) << 16;
  float f; __builtin_memcpy(&f, &u, 4); return f;
}
static __device__ __forceinline__ short f2bf(float f) {
  unsigned int u; __builtin_memcpy(&u, &f, 4);
  u += 0x7fffu + ((u >> 16) & 1u);   // round-to-nearest-even
  return (short)(u >> 16);
}

#if __has_builtin(__builtin_amdgcn_exp2f)
static __device__ __forceinline__ float fexp2(float x) { return __builtin_amdgcn_exp2f(x); }
#else
static __device__ __forceinline__ float fexp2(float x) { return exp2f(x); }
#endif

// async global->LDS, 16B per lane. LDS dest is wave-uniform base + lane*16.
static __device__ __forceinline__ void gl_lds16(const short* g, short* l) {
  __builtin_amdgcn_global_load_lds(
      (const __attribute__((address_space(1))) unsigned int*)g,
      (__attribute__((address_space(3))) unsigned int*)l, 16, 0, 0);
}

// DPP all-reduce across the 16 lanes of a DPP row (= our quad group).
template<int CTRL>
static __device__ __forceinline__ float dpp_movf(float x) {
  return __builtin_bit_cast(float, __builtin_amdgcn_update_dpp(
      0, __builtin_bit_cast(int, x), CTRL, 0xF, 0xF, true));
}
static __device__ __forceinline__ float row_max16(float v) {
  v = fmaxf(v, dpp_movf<0x128>(v));   // row_ror:8
  v = fmaxf(v, dpp_movf<0x124>(v));   // row_ror:4
  v = fmaxf(v, dpp_movf<0x122>(v));   // row_ror:2
  v = fmaxf(v, dpp_movf<0x121>(v));   // row_ror:1
  return v;
}
static __device__ __forceinline__ float row_sum16(float v) {
  v += dpp_movf<0x128>(v);
  v += dpp_movf<0x124>(v);
  v += dpp_movf<0x122>(v);
  v += dpp_movf<0x121>(v);
  return v;
}

// ---------------- kernel 1: ALL dtype conversions in one launch ----------------
// [0,4096): query hi/lo split. [4096,4608): inf1_w hi/lo split.
// [4608,5632) Wq, [5632,6656) Wk, [6656,7680) Wv, [7680,8704) Wo (plain bf16).
__global__ __launch_bounds__(256) void cvt_all(
    const float* __restrict__ query, const float* __restrict__ inf1_w,
    const float* __restrict__ qw, const float* __restrict__ kw,
    const float* __restrict__ vw, const float* __restrict__ ow,
    short* __restrict__ qh, short* __restrict__ ql,
    short* __restrict__ w1h, short* __restrict__ w1l,
    short* __restrict__ Wq, short* __restrict__ Wk,
    short* __restrict__ Wv, short* __restrict__ Wo)
{
  int blk = blockIdx.x;
  if (blk < 4608) {              // split sections
    const float* in; short *oh, *ol; int i;
    if (blk < 4096) { in = query;  oh = qh;  ol = ql;  i = (blk * 256 + threadIdx.x) * 4; }
    else            { in = inf1_w; oh = w1h; ol = w1l; i = ((blk - 4096) * 256 + threadIdx.x) * 4; }
    float4 f = *(const float4*)(in + i);
    union { short s[4]; uint2 v; } uh, ul;
    float x[4] = {f.x, f.y, f.z, f.w};
    #pragma unroll
    for (int u = 0; u < 4; ++u) {
      short h = f2bf(x[u]);
      uh.s[u] = h;
      ul.s[u] = f2bf(x[u] - bf2f(h));
    }
    *(uint2*)(oh + i) = uh.v;
    *(uint2*)(ol + i) = ul.v;
  } else {                       // plain bf16 sections (1024 blocks each)
    int t = blk - 4608;
    int mat = t >> 10, sub = t & 1023;
    const float* in = (mat == 0) ? qw : (mat == 1) ? kw : (mat == 2) ? vw : ow;
    short* out      = (mat == 0) ? Wq : (mat == 1) ? Wk : (mat == 2) ? Wv : Wo;
    int i = (sub * 256 + threadIdx.x) * 4;
    float4 f = *(const float4*)(in + i);
    union { short s[4]; uint2 v; } u;
    u.s[0] = f2bf(f.x); u.s[1] = f2bf(f.y); u.s[2] = f2bf(f.z); u.s[3] = f2bf(f.w);
    *(uint2*)(out + i) = u.v;
  }
}

// ---------------- m97-style 128x128 GEMM body (smem passed in) ----------------
template<bool F32OUT>
static __device__ __forceinline__ void gemm128_body(
    short* smem,
    const short* __restrict__ A, const short* __restrict__ B,
    const float* __restrict__ bias, void* __restrict__ outv,
    int row0, int col0, float scale)
{
  short* As = smem;              // 128*32
  short* Bs = smem + 128*32;     // 128*32
  const int tid  = threadIdx.x;
  const int wave = tid >> 6, lane = tid & 63;
  const int quad = lane >> 4, l16 = lane & 15;
  const int wr = wave >> 1, wc = wave & 1;
  const int lr = lane >> 2, lc8 = (lane & 3) * 8;

  const short* gA = A + (size_t)(row0 + wave*16 + lr) * EDIM + lc8;
  const short* gB = B + (size_t)(col0 + wave*16 + lr) * EDIM + lc8;
  short* lA = As + wave*512;
  short* lB = Bs + wave*512;

  f32x4 acc[4][4] = {};
  gl_lds16(gA, lA);  gl_lds16(gA + 64*EDIM, lA + 64*32);
  gl_lds16(gB, lB);  gl_lds16(gB + 64*EDIM, lB + 64*32);

  for (int k0 = 0; k0 < EDIM; k0 += 32) {
    __syncthreads();
    bf16x8 af[4], bfr[4];
    #pragma unroll
    for (int i = 0; i < 4; ++i)
      af[i] = *(const bf16x8*)&As[(wr*64 + i*16 + l16)*32 + quad*8];
    #pragma unroll
    for (int j = 0; j < 4; ++j)
      bfr[j] = *(const bf16x8*)&Bs[(wc*64 + j*16 + l16)*32 + quad*8];
    __syncthreads();
    if (k0 + 32 < EDIM) {
      const short* gA2 = gA + k0 + 32;
      const short* gB2 = gB + k0 + 32;
      gl_lds16(gA2, lA);  gl_lds16(gA2 + 64*EDIM, lA + 64*32);
      gl_lds16(gB2, lB);  gl_lds16(gB2 + 64*EDIM, lB + 64*32);
    }
    #pragma unroll
    for (int i = 0; i < 4; ++i)
      #pragma unroll
      for (int j = 0; j < 4; ++j)
        acc[i][j] = __builtin_amdgcn_mfma_f32_16x16x32_bf16(af[i], bfr[j], acc[i][j], 0, 0, 0);
  }
  #pragma unroll
  for (int j = 0; j < 4; ++j) {
    int col = col0 + wc*64 + j*16 + l16;
    float bv = bias[col];
    #pragma unroll
    for (int i = 0; i < 4; ++i) {
      int rowb = row0 + wr*64 + i*16 + quad*4;
      #pragma unroll
      for (int r = 0; r < 4; ++r) {
        float v = (acc[i][j][r] + bv) * scale;
        if constexpr (F32OUT) {
          ((float*)outv)[(size_t)(rowb + r) * EDIM + col] = v;
        } else {
          ((short*)outv)[(size_t)(rowb + r) * EDIM + col] = f2bf(v);
        }
      }
    }
  }
}

// t1 body: 128x64 tile, hi/lo-split (3 MFMAs, fp32-accurate), relu -> T1 fp32.
static __device__ __forceinline__ void gemm_t1_body(
    short* smem,
    const short* __restrict__ Agh, const short* __restrict__ Agl,
    const short* __restrict__ Bgh, const short* __restrict__ Bgl,
    const float* __restrict__ bias, float* __restrict__ T1,
    int row0, int col0)
{
  short* Ah = smem;              // 128*32
  short* Al = smem + 4096;      // 128*32
  short* Bh = smem + 8192;      // 64*32
  short* Bl = smem + 10240;     // 64*32
  const int tid  = threadIdx.x;
  const int wave = tid >> 6, lane = tid & 63;
  const int quad = lane >> 4, l16 = lane & 15;
  const int wr = wave >> 1, wc = wave & 1;
  const int lr = lane >> 2, lc8 = (lane & 3) * 8;

  const short* gAh = Agh + (size_t)(row0 + wave*16 + lr) * EDIM + lc8;
  const short* gAl = Agl + (size_t)(row0 + wave*16 + lr) * EDIM + lc8;
  const short* gBh = Bgh + (size_t)(col0 + wave*16 + lr) * EDIM + lc8;
  const short* gBl = Bgl + (size_t)(col0 + wave*16 + lr) * EDIM + lc8;
  short* lAh = Ah + wave*512;  short* lAl = Al + wave*512;
  short* lBh = Bh + wave*512;  short* lBl = Bl + wave*512;

  f32x4 acc[4][2] = {};
  gl_lds16(gAh, lAh);  gl_lds16(gAh + 64*EDIM, lAh + 64*32);
  gl_lds16(gAl, lAl);  gl_lds16(gAl + 64*EDIM, lAl + 64*32);
  gl_lds16(gBh, lBh);  gl_lds16(gBl, lBl);

  for (int k0 = 0; k0 < EDIM; k0 += 32) {
    __syncthreads();
    bf16x8 ah[4], al[4], bh[2], bl[2];
    #pragma unroll
    for (int i = 0; i < 4; ++i) {
      ah[i] = *(const bf16x8*)&Ah[(wr*64 + i*16 + l16)*32 + quad*8];
      al[i] = *(const bf16x8*)&Al[(wr*64 + i*16 + l16)*32 + quad*8];
    }
    #pragma unroll
    for (int j = 0; j < 2; ++j) {
      bh[j] = *(const bf16x8*)&Bh[(wc*32 + j*16 + l16)*32 + quad*8];
      bl[j] = *(const bf16x8*)&Bl[(wc*32 + j*16 + l16)*32 + quad*8];
    }
    __syncthreads();
    if (k0 + 32 < EDIM) {
      const short* p;
      p = gAh + k0 + 32;  gl_lds16(p, lAh);  gl_lds16(p + 64*EDIM, lAh + 64*32);
      p = gAl + k0 + 32;  gl_lds16(p, lAl);  gl_lds16(p + 64*EDIM, lAl + 64*32);
      gl_lds16(gBh + k0 + 32, lBh);  gl_lds16(gBl + k0 + 32, lBl);
    }
    #pragma unroll
    for (int i = 0; i < 4; ++i)
      #pragma unroll
      for (int j = 0; j < 2; ++j) {
        acc[i][j] = __builtin_amdgcn_mfma_f32_16x16x32_bf16(ah[i], bh[j], acc[i][j], 0, 0, 0);
        acc[i][j] = __builtin_amdgcn_mfma_f32_16x16x32_bf16(ah[i], bl[j], acc[i][j], 0, 0, 0);
        acc[i][j] = __builtin_amdgcn_mfma_f32_16x16x32_bf16(al[i], bh[j], acc[i][j], 0, 0, 0);
      }
  }
  #pragma unroll
  for (int j = 0; j < 2; ++j) {
    int col = col0 + wc*32 + j*16 + l16;
    float bv = bias[col];
    #pragma unroll
    for (int i = 0; i < 4; ++i) {
      int rowb = row0 + wr*64 + i*16 + quad*4;
      #pragma unroll
      for (int r = 0; r < 4; ++r)
        T1[(size_t)(rowb + r) * HIDDEN + col] = fmaxf(acc[i][j][r] + bv, 0.0f);
    }
  }
}

// ---------------- kernel 2: t1 GEMM + QKV GEMM, interleaved 1:3 ----------------
// (blk&3)==3 -> t1 block (256 of 1024); else qkv block (768 of 1024).
// t1's standalone 1-block/CU under-occupancy is cured by co-residency with
// qkv blocks (MFMA+VALU pipes shared across waves of both kinds).
__global__ __launch_bounds__(256) void mega_gemm1(
    const short* __restrict__ qh, const short* __restrict__ ql,
    const short* __restrict__ w1h, const short* __restrict__ w1l,
    const float* __restrict__ inf1_b, float* __restrict__ T1,
    const short* __restrict__ Wq, const short* __restrict__ Wk,
    const short* __restrict__ Wv,
    const float* __restrict__ qb, const float* __restrict__ kb,
    const float* __restrict__ vb,
    short* __restrict__ Qp, short* __restrict__ Kp, short* __restrict__ Vp)
{
  __shared__ __attribute__((aligned(16))) short smem[12288];   // 24 KB union
  int blk = blockIdx.x;
  if ((blk & 3) == 3) {
    int id = blk >> 2;                         // [0,256)
    gemm_t1_body(smem, qh, ql, w1h, w1l, inf1_b, T1,
                 (id & 31) * 128, (id >> 5) * 64);
  } else {
    int id = (blk >> 2) * 3 + (blk & 3);       // [0,768)
    int row0 = (id & 31) * 128;
    int rest = id >> 5;                        // [0,24)
    int mat = rest >> 3, cb = rest & 7;
    const short* B   = (mat == 0) ? Wq : (mat == 1) ? Wk : Wv;
    const float* bia = (mat == 0) ? qb : (mat == 1) ? kb : vb;
    short* out       = (mat == 0) ? Qp : (mat == 1) ? Kp : Vp;
    // q scale folds D^-0.5 * log2(e) (flash softmax runs in exp2 domain)
    float scale      = (mat == 0) ? 0.18033688011112042f : 1.0f;
    gemm128_body<false>(smem, qh, B, bia, (void*)out, row0, cb * 128, scale);
  }
}

// ---------------- kernel 3: head-mask + V-transpose in one launch ----------------
__global__ __launch_bounds__(256) void mid_kernel(
    const float* __restrict__ T1, const float* __restrict__ inf2_w,
    const float* __restrict__ inf2_b, const float* __restrict__ head_sig,
    float* __restrict__ maskbuf,
    const short* __restrict__ Vp, short* __restrict__ VT)
{
  __shared__ __attribute__((aligned(16))) float fsm[16*HIDDEN + 16*SIGD + 16*NHEAD];
  int blk = blockIdx.x;
  const int tid = threadIdx.x;
  if (blk < 256) {
    // ---- head mask: t2 = t1 @ inf2_w^T + b ; s = t2 @ head_sig^T ; top-12 ----
    float (*t1s)[HIDDEN] = (float(*)[HIDDEN])fsm;
    float (*t2s)[SIGD]   = (float(*)[SIGD])(fsm + 16*HIDDEN);
    float (*ss)[NHEAD]   = (float(*)[NHEAD])(fsm + 16*HIDDEN + 16*SIGD);
    const int tok0 = blk * 16;
    {
      int row = tid >> 4, c0 = (tid & 15) * 32;
      const float* src = T1 + (size_t)(tok0 + row) * HIDDEN + c0;
      #pragma unroll
      for (int u = 0; u < 8; ++u)
        *(float4*)&t1s[row][c0 + u*4] = *(const float4*)(src + u*4);
    }
    __syncthreads();
    #pragma unroll
    for (int it = 0; it < 4; ++it) {
      int idx = tid + it * 256;
      int tok = idx >> 6, j = idx & 63;
      const float4* w4 = (const float4*)(inf2_w + (size_t)j * HIDDEN);
      const float4* t4 = (const float4*)(&t1s[tok][0]);
      float a = inf2_b[j];
      for (int k = 0; k < HIDDEN/4; ++k) {
        float4 wv = w4[k], tv = t4[k];
        a += tv.x*wv.x + tv.y*wv.y + tv.z*wv.z + tv.w*wv.w;
      }
      t2s[tok][j] = a;
    }
    __syncthreads();
    {
      int tok = tid >> 4, h = tid & 15;
      float a = 0.f;
      for (int d = 0; d < SIGD; ++d) a += t2s[tok][d] * head_sig[h*SIGD + d];
      ss[tok][h] = a;
    }
    __syncthreads();
    {
      int tok = tid >> 4, h = tid & 15;
      float sv = ss[tok][h];
      int cnt = 0;
      #pragma unroll
      for (int j = 0; j < NHEAD; ++j) cnt += (ss[tok][j] > sv) ? 1 : 0;
      int gt = tok0 + tok;
      int s = gt >> 1, b = gt & 1;             // token row = s*B + b
      maskbuf[((size_t)(b*NHEAD + h)) * S_LEN + s] = (cnt < KEEP) ? 1.0f : 0.0f;
    }
  } else {
    // ---- V transpose: Vp (token-major) -> VT[(b*16+h)*64+d][S_LEN] ----
    short (*tile)[72] = (short(*)[72])fsm;
    int t = blk - 256;                          // [0,1024)
    const int s0 = (t & 31) * 64, e0 = ((t >> 5) & 15) * 64, b = t >> 9;
    {
      int sr = tid >> 2, ec = (tid & 3) * 16;
      const short* src = Vp + (size_t)(s0 + sr) * 2048 + b * 1024 + e0 + ec;
      *(uint4*)&tile[sr][ec]     = *(const uint4*)src;
      *(uint4*)&tile[sr][ec + 8] = *(const uint4*)(src + 8);
    }
    __syncthreads();
    {
      int er = tid >> 2, sc = (tid & 3) * 16;
      unsigned pack[8];
      #pragma unroll
      for (int u = 0; u < 8; ++u) {
        unsigned lo = (unsigned short)tile[sc + 2*u][er];
        unsigned hi = (unsigned short)tile[sc + 2*u + 1][er];
        pack[u] = lo | (hi << 16);
      }
      short* dst = VT + (size_t)(b * 1024 + e0 + er) * 2048 + s0 + sc;
      *(uint4*)(dst)     = *(uint4*)&pack[0];
      *(uint4*)(dst + 8) = *(uint4*)&pack[4];
    }
  }
}

// ---------------- kernel 4: flash attention (exp2 domain) ----------------
__global__ __launch_bounds__(256) void flash_attn(
    short* QpOg, const short* __restrict__ Kp, const short* __restrict__ VT,
    const float* __restrict__ maskbuf)
{
  __shared__ __attribute__((aligned(16))) short Ks[128][72];   // 18432 B
  __shared__ __attribute__((aligned(16))) short Vt[64*136];    // 17408 B
  __shared__ __attribute__((aligned(16))) short uni[8704];     // Qstage 64x72 | Ps 4x16x136
  const int bh = blockIdx.x;
  const int b = bh >> 4, h = bh & 15;
  const int q0 = blockIdx.y * 64;
  const int tid = threadIdx.x;
  const int wave = tid >> 6, lane = tid & 63;
  const int quad = lane >> 4, l16 = lane & 15;
  const size_t colbase = (size_t)b * EDIM + h * DHEAD;
  const size_t rstride = (size_t)BATCH * EDIM;   // 2048
  const short* VTbase = VT + (size_t)(bh * 64) * S_LEN;
  {
    int r = tid >> 2, d0 = (tid & 3) * 16;
    const short* src = QpOg + (size_t)(q0 + r) * rstride + colbase + d0;
    *(uint4*)&uni[r*72 + d0]     = *(const uint4*)src;
    *(uint4*)&uni[r*72 + d0 + 8] = *(const uint4*)(src + 8);
  }
  __syncthreads();
  bf16x8 aq0 = *(const bf16x8*)&uni[(wave*16 + l16)*72 + quad*8];
  bf16x8 aq1 = *(const bf16x8*)&uni[(wave*16 + l16)*72 + 32 + quad*8];
  short* Psw = &uni[wave * 2176];        // per-wave 16 x 136

  float m_i[4], l_i[4];
  f32x4 oacc[4];
  #pragma unroll
  for (int r = 0; r < 4; ++r) { m_i[r] = -1e30f; l_i[r] = 0.f; }
  #pragma unroll
  for (int dt = 0; dt < 4; ++dt) oacc[dt] = f32x4{0.f, 0.f, 0.f, 0.f};

  const int vd  = tid >> 2;
  const int vcc = (((tid & 3) + vd) & 3) * 32;

  for (int kv0 = 0; kv0 < S_LEN; kv0 += 128) {
    __syncthreads();
    {  // stage K: 128 rows x 64
      int r = tid >> 1, c0 = (tid & 1) * 32;
      const short* src = Kp + (size_t)(kv0 + r) * rstride + colbase + c0;
      short* dst = &Ks[r][c0];
      *(uint4*)(dst)      = *(const uint4*)(src);
      *(uint4*)(dst + 8)  = *(const uint4*)(src + 8);
      *(uint4*)(dst + 16) = *(const uint4*)(src + 16);
      *(uint4*)(dst + 24) = *(const uint4*)(src + 24);
    }
    {  // stage V^T: 64 rows (d) x 128 cols (kv); 32 shorts/thread
      const short* src = VTbase + (size_t)vd * S_LEN + kv0 + vcc;
      short* dst = &Vt[vd*136 + vcc];
      *(uint4*)(dst)      = *(const uint4*)(src);
      *(uint4*)(dst + 8)  = *(const uint4*)(src + 8);
      *(uint4*)(dst + 16) = *(const uint4*)(src + 16);
      *(uint4*)(dst + 24) = *(const uint4*)(src + 24);
    }
    __syncthreads();
    f32x4 sacc[8];
    #pragma unroll
    for (int c = 0; c < 8; ++c) sacc[c] = f32x4{0.f, 0.f, 0.f, 0.f};
    #pragma unroll
    for (int c = 0; c < 8; ++c) {
      bf16x8 b0 = *(const bf16x8*)&Ks[c*16 + l16][quad*8];
      bf16x8 b1 = *(const bf16x8*)&Ks[c*16 + l16][32 + quad*8];
      sacc[c] = __builtin_amdgcn_mfma_f32_16x16x32_bf16(aq0, b0, sacc[c], 0, 0, 0);
      sacc[c] = __builtin_amdgcn_mfma_f32_16x16x32_bf16(aq1, b1, sacc[c], 0, 0, 0);
    }
    #pragma unroll
    for (int r = 0; r < 4; ++r) {
      float vmax = sacc[0][r];
      #pragma unroll
      for (int c = 1; c < 8; ++c) vmax = fmaxf(vmax, sacc[c][r]);
      vmax = row_max16(vmax);
      float mnew = fmaxf(m_i[r], vmax);
      float alpha = fexp2(m_i[r] - mnew);
      float rsum = 0.f;
      short* prow = &Psw[(quad*4 + r)*136 + l16];
      #pragma unroll
      for (int p = 0; p < 4; ++p) {
        float ea = fexp2(sacc[2*p][r]   - mnew);
        float eb = fexp2(sacc[2*p+1][r] - mnew);
        unsigned pk = __builtin_amdgcn_perm(
            __builtin_bit_cast(unsigned, eb),
            __builtin_bit_cast(unsigned, ea), 0x07060302u);
        prow[(2*p)*16]     = (short)(pk & 0xffffu);
        prow[(2*p + 1)*16] = (short)(pk >> 16);
        rsum += ea + eb;
      }
      rsum = row_sum16(rsum);
      l_i[r] = l_i[r] * alpha + rsum;
      m_i[r] = mnew;
      #pragma unroll
      for (int dt = 0; dt < 4; ++dt) oacc[dt][r] *= alpha;
    }
    asm volatile("s_waitcnt lgkmcnt(0)" ::: "memory");   // Ps visible (same wave)
    #pragma unroll
    for (int ks = 0; ks < 4; ++ks) {
      bf16x8 ap = *(const bf16x8*)&Psw[l16*136 + ks*32 + quad*8];
      #pragma unroll
      for (int dt = 0; dt < 4; ++dt) {
        bf16x8 bb = *(const bf16x8*)&Vt[(dt*16 + l16)*136 + ks*32 + quad*8];
        oacc[dt] = __builtin_amdgcn_mfma_f32_16x16x32_bf16(ap, bb, oacc[dt], 0, 0, 0);
      }
    }
  }
  #pragma unroll
  for (int r = 0; r < 4; ++r) {
    int s = q0 + wave*16 + quad*4 + r;
    float mk = maskbuf[((size_t)(b*NHEAD + h)) * S_LEN + s];
    float scale = mk / l_i[r];
    short* dst = QpOg + (size_t)s * rstride + colbase;
    #pragma unroll
    for (int dt = 0; dt < 4; ++dt)
      dst[dt*16 + l16] = f2bf(oacc[dt][r] * scale);
  }
}

// ---------------- kernel 5: out projection ----------------
__global__ __launch_bounds__(256) void gemm_out(
    const short* __restrict__ A, const short* __restrict__ W,
    const float* __restrict__ bias, float* __restrict__ out)
{
  __shared__ __attribute__((aligned(16))) short smem[8192];
  gemm128_body<true>(smem, A, W, bias, (void*)out,
                     blockIdx.x * 128, blockIdx.y * 128, 1.0f);
}

extern "C" void kernel_launch(void* const* d_in, const int* in_sizes, int n_in,
                              void* d_out, int out_size, void* d_ws, size_t ws_size,
                              hipStream_t stream)
{
  const float* query   = (const float*)d_in[0];
  const float* q_w     = (const float*)d_in[1];
  const float* q_b     = (const float*)d_in[2];
  const float* k_w     = (const float*)d_in[3];
  const float* k_b     = (const float*)d_in[4];
  const float* v_w     = (const float*)d_in[5];
  const float* v_b     = (const float*)d_in[6];
  const float* out_w   = (const float*)d_in[7];
  const float* out_b   = (const float*)d_in[8];
  const float* inf1_w  = (const float*)d_in[9];
  const float* inf1_b  = (const float*)d_in[10];
  const float* inf2_w  = (const float*)d_in[11];
  const float* inf2_b  = (const float*)d_in[12];
  const float* head_sig= (const float*)d_in[13];

  // ws (>= 42 MB, proven by R2's 42 MB footprint):
  //  [0,8)  qh   -> VT after mid_kernel (qh dead post mega_gemm1)
  //  [8,16) ql   -> maskbuf (256 KB) after mega_gemm1
  //  [16,24) Qp  -> gated O (flash in-place)
  //  [24,32) Kp
  //  [32,40) Vp  (dead after mid_kernel)
  //  [40,42) Wo  (written by cvt_all, read by gemm_out; untouched between)
  char* ws = (char*)d_ws;
  short* qh      = (short*)(ws);
  short* VTb     = (short*)(ws);
  short* ql      = (short*)(ws + (size_t)( 8u<<20));
  float* maskbuf = (float*)(ws + (size_t)( 8u<<20));
  short* Qp      = (short*)(ws + (size_t)(16u<<20));
  short* Kp      = (short*)(ws + (size_t)(24u<<20));
  short* Vp      = (short*)(ws + (size_t)(32u<<20));
  short* Wo      = (short*)(ws + (size_t)(40u<<20));
  // d_out (16 MB fp32) as scratch until gemm_out overwrites all of it:
  //  [0,8) T1 fp32 ; [8,9) w1h ; [9,10) w1l ; [10,12) Wq ; [12,14) Wk ; [14,16) Wv
  char* ob = (char*)d_out;
  float* T1  = (float*)(ob);
  short* w1h = (short*)(ob + (size_t)( 8u<<20));
  short* w1l = (short*)(ob + (size_t)( 9u<<20));
  short* Wq  = (short*)(ob + (size_t)(10u<<20));
  short* Wk  = (short*)(ob + (size_t)(12u<<20));
  short* Wv  = (short*)(ob + (size_t)(14u<<20));
  float* out = (float*)d_out;

  dim3 blk(256);
  cvt_all<<<dim3(8704), blk, 0, stream>>>(query, inf1_w, q_w, k_w, v_w, out_w,
                                          qh, ql, w1h, w1l, Wq, Wk, Wv, Wo);
  mega_gemm1<<<dim3(1024), blk, 0, stream>>>(qh, ql, w1h, w1l, inf1_b, T1,
                                             Wq, Wk, Wv, q_b, k_b, v_b, Qp, Kp, Vp);
  mid_kernel<<<dim3(1280), blk, 0, stream>>>(T1, inf2_w, inf2_b, head_sig, maskbuf,
                                             Vp, VTb);
  flash_attn<<<dim3(32, 32), blk, 0, stream>>>(Qp, Kp, VTb, maskbuf);
  gemm_out<<<dim3(32, 8), blk, 0, stream>>>(Qp, Wo, out_b, out);
}